// Round 7
// baseline (482.087 us; speedup 1.0000x reference)
//
#include <hip/hip_runtime.h>
#include <hip/hip_fp16.h>
#include <math.h>

#define NB 32
#define NTOK 4096
#define DIM 256
#define NS 8
#define HID 512
#define NCHUNK 32
#define LN_EPS 1e-5f
#define ATT_EPS 1e-8f
#define SCALE 0.0625f
#define NROWS (NB * NS)   // 256

// ---- cross-lane primitives (VALU-pipe: DPP / permlane) ---------------------
#define DPPF(x, ctrl) __int_as_float(__builtin_amdgcn_update_dpp(0, __float_as_int(x), (ctrl), 0xF, 0xF, true))
// 0xB1 quad_perm xor1, 0x4E quad_perm xor2, 0x141 row_half_mirror (xor7),
// 0x124 row_ror:4, 0x128 row_ror:8

__device__ __forceinline__ float addx16(float c) {
#if __has_builtin(__builtin_amdgcn_permlane16_swap)
    auto r = __builtin_amdgcn_permlane16_swap(__float_as_uint(c), __float_as_uint(c), false, false);
    return __uint_as_float(r[0]) + __uint_as_float(r[1]);
#else
    return c + __shfl_xor(c, 16);
#endif
}
__device__ __forceinline__ float addx32(float c) {
#if __has_builtin(__builtin_amdgcn_permlane32_swap)
    auto r = __builtin_amdgcn_permlane32_swap(__float_as_uint(c), __float_as_uint(c), false, false);
    return __uint_as_float(r[0]) + __uint_as_float(r[1]);
#else
    return c + __shfl_xor(c, 32);
#endif
}

// sum + sumsq over 64 lanes, both results in every lane.
__device__ __forceinline__ void tree2(float v0, float v1, int lane, float& S, float& Q) {
    bool hi = lane & 1;
    float send = hi ? v0 : v1;
    float recv = DPPF(send, 0xB1);
    float a = (hi ? v1 : v0) + recv;
    a += DPPF(a, 0x4E);
    a += DPPF(a, 0x124);
    a += DPPF(a, 0x128);
    a = addx16(a);
    a = addx32(a);
    float other = DPPF(a, 0xB1);
    S = hi ? other : a;
    Q = hi ? a : other;
}

// sum + sumsq over each 16-lane group, results in every lane of the group.
__device__ __forceinline__ void tree2_16(float v0, float v1, int lane, float& S, float& Q) {
    bool hi = lane & 1;
    float send = hi ? v0 : v1;
    float recv = DPPF(send, 0xB1);
    float a = (hi ? v1 : v0) + recv;
    a += DPPF(a, 0x4E);
    a += DPPF(a, 0x124);
    a += DPPF(a, 0x128);
    float other = DPPF(a, 0xB1);
    S = hi ? other : a;
    Q = hi ? a : other;
}

// 8 independent sums over a 32-lane half-wave; lane ends with full half-wave
// sum of slot sig(lane) = (l0<<2)|(l1<<1)|(l0^l1^l2).
__device__ __forceinline__ float tree8h(const float v[8], int lane) {
    bool b0 = lane & 1;
    bool b1 = lane & 2;
    bool bp = ((lane ^ (lane >> 1) ^ (lane >> 2)) & 1);
    float a[4];
#pragma unroll
    for (int j = 0; j < 4; j++) {
        float send = b0 ? v[j] : v[4 + j];
        float recv = DPPF(send, 0xB1);
        a[j] = (b0 ? v[4 + j] : v[j]) + recv;
    }
    float b[2];
#pragma unroll
    for (int j = 0; j < 2; j++) {
        float send = b1 ? a[j] : a[2 + j];
        float recv = DPPF(send, 0x4E);
        b[j] = (b1 ? a[2 + j] : a[j]) + recv;
    }
    float send = bp ? b[0] : b[1];
    float recv = DPPF(send, 0x141);
    float c = (bp ? b[1] : b[0]) + recv;
    c += DPPF(c, 0x128);
    c = addx16(c);
    return c;
}

typedef _Float16 h2v __attribute__((ext_vector_type(2)));
__device__ __forceinline__ float fdot2u(unsigned a, unsigned b, float c) {
#if __has_builtin(__builtin_amdgcn_fdot2)
    return __builtin_amdgcn_fdot2(__builtin_bit_cast(h2v, a), __builtin_bit_cast(h2v, b), c, false);
#else
    __half2 ha = __builtin_bit_cast(__half2, a), hb = __builtin_bit_cast(__half2, b);
    return c + __low2float(ha) * __low2float(hb) + __high2float(ha) * __high2float(hb);
#endif
}
__device__ __forceinline__ unsigned pkh(float a, float b) {
    return __builtin_bit_cast(unsigned, __floats2half2_rn(a, b));
}

// ================= K1: weight prep (role-switched) ===========================
#define WP_W2C0 257
#define WP_F1B0 305
#define WP_B2G0 307
#define WP_TR0  310
#define WP_BLKS 1462

__global__ void __launch_bounds__(256)
k_wprep(const float* __restrict__ wq, const float* __restrict__ wk,
        const float* __restrict__ bk, const float* __restrict__ bq,
        const float* __restrict__ lsb, const float* __restrict__ lsw,
        float* __restrict__ Mpp, float* __restrict__ u2p, float* __restrict__ biasp,
        const float* __restrict__ wv, const float* __restrict__ wih,
        float* __restrict__ w2c,
        const float* __restrict__ f1w, const float* __restrict__ f1b,
        const float* __restrict__ lfb, float* __restrict__ f1bp,
        const float* __restrict__ bih, const float* __restrict__ bv,
        float* __restrict__ b2g,
        const float* __restrict__ whh, const float* __restrict__ f2w,
        const float* __restrict__ lfw,
        float* __restrict__ whhT, float* __restrict__ f1Tp, float* __restrict__ f2T) {
    int bid = blockIdx.x, t = threadIdx.x;

    if (bid < WP_W2C0) {                       // ---- Mpp / biasp / u2p / k2
        int e = bid, o = t;
        bool isBias = (e == 256);
        __shared__ float t2l[256];
        __shared__ float red[256], red2[32];
        if (isBias) {
            float a = bq[o];
            for (int k = 0; k < 256; k++) a = fmaf(wq[(size_t)o * 256 + k], lsb[k], a);
            t2l[o] = a;
        }
        __syncthreads();
        float acc = 0.f;
        for (int d = 0; d < 256; d++)
            acc = fmaf(isBias ? t2l[d] : wq[(size_t)d * 256 + e], wk[(size_t)d * 256 + o], acc);
        red[o] = (isBias ? t2l[o] : wq[(size_t)o * 256 + e]) * bk[o];
        __syncthreads();
        if (o < 32) {
            float s = 0.f;
            for (int k = 0; k < 8; k++) s += red[o * 8 + k];
            red2[o] = s;
        }
        __syncthreads();
        if (o == 0) {
            float s = 0.f;
            for (int k = 0; k < 32; k++) s += red2[k];
            if (isBias) biasp[256] = s;
            else u2p[e] = s * lsw[e];
        }
        if (isBias) biasp[o] = acc;
        else Mpp[(size_t)e * 256 + o] = acc * lsw[e];
        return;
    }
    if (bid < WP_F1B0) {                       // ---- w2c[e][o] = sum_d wv[d][e]*wih[o][d]
        int r = bid - WP_W2C0;
        int et = r & 3, ot = r >> 2;
        int e = et * 64 + (t & 63), og = (t >> 6) * 16;
        float acc[16] = {};
        for (int d = 0; d < 256; d++) {
            float v = wv[(size_t)d * 256 + e];
#pragma unroll
            for (int i = 0; i < 16; i++)
                acc[i] = fmaf(wih[(size_t)(ot * 64 + og + i) * 256 + d], v, acc[i]);
        }
#pragma unroll
        for (int i = 0; i < 16; i++)
            w2c[(size_t)e * 768 + ot * 64 + og + i] = acc[i];
        return;
    }
    if (bid < WP_B2G0) {                       // ---- f1bp
        int h = (bid - WP_F1B0) * 256 + t;
        float a = f1b[h];
        for (int e = 0; e < 256; e++) a = fmaf(f1w[(size_t)h * 256 + e], lfb[e], a);
        f1bp[h] = a;
        return;
    }
    if (bid < WP_TR0) {                        // ---- b2g
        int o = (bid - WP_B2G0) * 256 + t;
        float a = bih[o];
        for (int d = 0; d < 256; d++) a = fmaf(wih[(size_t)o * 256 + d], bv[d], a);
        b2g[o] = a;
        return;
    }
    {                                          // ---- transposes
        int r = bid - WP_TR0;
        int z = r / 384, rem = r % 384;
        int by = rem >> 4, bx = rem & 15;
        __shared__ float tile[32][33];
        const float* in; float* out; const float* scl = nullptr; int R, C;
        switch (z) {
            case 0:  in = whh; out = whhT; R = 768; C = 256; break;
            case 1:  in = f1w; out = f1Tp; R = 512; C = 256; scl = lfw; break;
            default: in = f2w; out = f2T;  R = 256; C = 512; break;
        }
        int r0 = by * 32, c0 = bx * 32;
        if (r0 >= R || c0 >= C) return;
        int tx = t & 31, ty = t >> 5;
#pragma unroll
        for (int i = 0; i < 32; i += 8)
            tile[ty + i][tx] = in[(size_t)(r0 + ty + i) * C + (c0 + tx)];
        __syncthreads();
#pragma unroll
        for (int i = 0; i < 32; i += 8) {
            float s = scl ? scl[c0 + ty + i] : 1.f;
            out[(size_t)(c0 + ty + i) * R + (r0 + tx)] = tile[tx][ty + i] * s;
        }
    }
}

// ================= K2: xn -> f16 (pipelined) + slots init + first qk =========
#define XN_BLKS 2048
#define XN_TOTAL 2080

__global__ void __launch_bounds__(256)
k_xn(const float* __restrict__ x, const float* __restrict__ liw,
     const float* __restrict__ lib, __half* __restrict__ xh,
     const float* __restrict__ noise, const float* __restrict__ mu,
     const float* __restrict__ sg, float* __restrict__ slots,
     const float* __restrict__ Mpp, const float* __restrict__ biasp,
     const float* __restrict__ u2p,
     float* __restrict__ qkw, float* __restrict__ c2b) {
    int bid = blockIdx.x, t = threadIdx.x;
    int wave = t >> 6, lane = t & 63;

    if (bid < XN_BLKS) {
        int g = lane >> 4, il = lane & 15;
        float4 wb[4], bb4[4];
#pragma unroll
        for (int k = 0; k < 4; k++) {
            wb[k]  = *(const float4*)&liw[il * 4 + k * 64];
            bb4[k] = *(const float4*)&lib[il * 4 + k * 64];
        }
        size_t row0 = (size_t)bid * 64 + wave * 4 + g;
        const float* xp = x + row0 * 256 + il * 4;
        __half* op = xh + row0 * 256 + il * 4;
        float4 c[4];
#pragma unroll
        for (int k = 0; k < 4; k++) c[k] = *(const float4*)(xp + k * 64);
#pragma unroll
        for (int it = 0; it < 4; it++) {
            float4 n[4];
            if (it < 3) {
#pragma unroll
                for (int k = 0; k < 4; k++)
                    n[k] = *(const float4*)(xp + (size_t)(it + 1) * 4096 + k * 64);
            }
            float s1 = 0.f, s2 = 0.f;
#pragma unroll
            for (int k = 0; k < 4; k++) {
                s1 += c[k].x + c[k].y + c[k].z + c[k].w;
                s2 += c[k].x * c[k].x + c[k].y * c[k].y + c[k].z * c[k].z + c[k].w * c[k].w;
            }
            float S, Q;
            tree2_16(s1, s2, lane, S, Q);
            float m = S * (1.f / DIM);
            float rstd = rsqrtf(Q * (1.f / DIM) - m * m + LN_EPS);
#pragma unroll
            for (int k = 0; k < 4; k++) {
                float z0 = (c[k].x - m) * rstd * wb[k].x + bb4[k].x;
                float z1 = (c[k].y - m) * rstd * wb[k].y + bb4[k].y;
                float z2 = (c[k].z - m) * rstd * wb[k].z + bb4[k].z;
                float z3 = (c[k].w - m) * rstd * wb[k].w + bb4[k].w;
                uint2 st;
                st.x = pkh(z0, z1);
                st.y = pkh(z2, z3);
                *(uint2*)(op + (size_t)it * 4096 + k * 64) = st;
            }
            if (it < 3) {
#pragma unroll
                for (int k = 0; k < 4; k++) c[k] = n[k];
            }
        }
        return;
    }
    // ---- slots init + first qk
    {
        int bb = bid - XN_BLKS;
        __shared__ float S2[NS][DIM], Zl[NS][DIM];
#pragma unroll
        for (int k = 0; k < 8; k++) {
            int idx = k * 256 + t, d = idx & 255;
            float v = mu[d] + sg[d] * noise[(size_t)bb * 2048 + idx];
            S2[idx >> 8][d] = v;
            slots[(size_t)bb * 2048 + idx] = v;
        }
        __syncthreads();
#pragma unroll
        for (int rr = 0; rr < 2; rr++) {
            int r = wave * 2 + rr;
            float4 xv = *(const float4*)&S2[r][lane * 4];
            float S, Q;
            tree2(xv.x + xv.y + xv.z + xv.w,
                  xv.x * xv.x + xv.y * xv.y + xv.z * xv.z + xv.w * xv.w, lane, S, Q);
            float m = S * (1.f / DIM);
            float rstd = rsqrtf(Q * (1.f / DIM) - m * m + LN_EPS);
            Zl[r][lane * 4 + 0] = (xv.x - m) * rstd;
            Zl[r][lane * 4 + 1] = (xv.y - m) * rstd;
            Zl[r][lane * 4 + 2] = (xv.z - m) * rstd;
            Zl[r][lane * 4 + 3] = (xv.w - m) * rstd;
        }
        __syncthreads();
        float acc[8] = {};
        for (int e = 0; e < 256; e++) {
            float w = Mpp[(size_t)e * 256 + t];
#pragma unroll
            for (int i = 0; i < 8; i++) acc[i] = fmaf(Zl[i][e], w, acc[i]);
        }
        float bo = biasp[t];
#pragma unroll
        for (int i = 0; i < 8; i++)
            qkw[(size_t)(bb * NS + i) * DIM + t] = acc[i] + bo;
        if (t < 64) {
            int s = t >> 3, j = t & 7;
            float a = 0.f;
            for (int e = j * 32; e < j * 32 + 32; e++) a = fmaf(Zl[s][e], u2p[e], a);
            a += DPPF(a, 0xB1);
            a += DPPF(a, 0x4E);
            a += DPPF(a, 0x141);
            if (j == 0) c2b[bb * NS + s] = a + biasp[256];
        }
    }
}

// ================= per-iter: fused attention =================================
__global__ void __launch_bounds__(256, 3)
k_attn(const __half* __restrict__ xh, const float* __restrict__ qkw,
       const float* __restrict__ c2b,
       float* __restrict__ pu, float* __restrict__ pda) {
    const int bb = blockIdx.x, chunk = blockIdx.y;
    const int t = threadIdx.x, wave = t >> 6, lane = t & 63;
    const int l0 = lane & 1, l1 = (lane >> 1) & 1, l2 = (lane >> 2) & 1;
    const int sig = (l0 << 2) | (l1 << 1) | (l0 ^ l1 ^ l2);
    const int e0 = (lane & 31) * 8;

    unsigned qh[NS][4];
#pragma unroll
    for (int s = 0; s < NS; s++) {
        const float4 a = *(const float4*)&qkw[(size_t)(bb * NS + s) * DIM + e0];
        const float4 b = *(const float4*)&qkw[(size_t)(bb * NS + s) * DIM + e0 + 4];
        qh[s][0] = pkh(a.x, a.y); qh[s][1] = pkh(a.z, a.w);
        qh[s][2] = pkh(b.x, b.y); qh[s][3] = pkh(b.z, b.w);
    }
    const float qbs = c2b[bb * NS + sig] * SCALE;

    float ua[NS][8] = {};
    float da[NS] = {};

    const __half* xp = xh + ((size_t)bb * NTOK + chunk * 128 + wave * 32 + (lane >> 5)) * DIM + e0;
    uint4 nxt = *(const uint4*)xp;
    for (int i = 0; i < 16; i++) {
        uint4 xv = nxt;
        if (i < 15) nxt = *(const uint4*)(xp + (size_t)(i + 1) * 2 * DIM);
        float dp[NS];
#pragma unroll
        for (int s = 0; s < NS; s++)
            dp[s] = fdot2u(qh[s][0], xv.x, fdot2u(qh[s][1], xv.y,
                    fdot2u(qh[s][2], xv.z, fdot2u(qh[s][3], xv.w, 0.f))));
        float ds = tree8h(dp, lane);
        float dv = fmaf(ds, SCALE, qbs);
        float mx = dv;
        mx = fmaxf(mx, DPPF(mx, 0xB1));
        mx = fmaxf(mx, DPPF(mx, 0x4E));
        mx = fmaxf(mx, DPPF(mx, 0x141));
        float e = __expf(dv - mx);
        float sm = e;
        sm += DPPF(sm, 0xB1);
        sm += DPPF(sm, 0x4E);
        sm += DPPF(sm, 0x141);
        float g0 = fmaf(e, __fdividef(1.f, sm), ATT_EPS);
        float g1 = DPPF(g0, 0x141);
        float g2 = DPPF(g0, 0x4E);
        float g3 = DPPF(g1, 0x4E);
        float g4 = DPPF(g0, 0xB1);
        float g5 = DPPF(g1, 0xB1);
        float g6 = DPPF(g2, 0xB1);
        float g7 = DPPF(g3, 0xB1);
        float gth[NS] = {g0, g1, g2, g3, g4, g5, g6, g7};
        __half2 p0 = __builtin_bit_cast(__half2, xv.x);
        __half2 p1 = __builtin_bit_cast(__half2, xv.y);
        __half2 p2 = __builtin_bit_cast(__half2, xv.z);
        __half2 p3 = __builtin_bit_cast(__half2, xv.w);
        float xf[8] = {__low2float(p0), __high2float(p0), __low2float(p1), __high2float(p1),
                       __low2float(p2), __high2float(p2), __low2float(p3), __high2float(p3)};
#pragma unroll
        for (int j = 0; j < NS; j++) {
            float pj = gth[j];
            da[j] += pj;
#pragma unroll
            for (int k = 0; k < 8; k++) ua[j][k] = fmaf(pj, xf[k], ua[j][k]);
        }
    }
#pragma unroll
    for (int j = 0; j < NS; j++) {
        da[j] = addx32(da[j]);
#pragma unroll
        for (int k = 0; k < 8; k++) ua[j][k] = addx32(ua[j][k]);
    }
    __shared__ float ul[4][NS][DIM];
    __shared__ float dl[4][NS];
    const int M8[NS] = {0, 7, 3, 4, 5, 2, 6, 1};
    if (lane < 32) {
#pragma unroll
        for (int j = 0; j < NS; j++) {
            int sj = sig ^ M8[j];
            *(float4*)&ul[wave][sj][e0]     = float4{ua[j][0], ua[j][1], ua[j][2], ua[j][3]};
            *(float4*)&ul[wave][sj][e0 + 4] = float4{ua[j][4], ua[j][5], ua[j][6], ua[j][7]};
        }
    }
    if (lane < 8) {
#pragma unroll
        for (int j = 0; j < NS; j++) dl[wave][sig ^ M8[j]] = da[j];
    }
    __syncthreads();
    size_t base = ((size_t)bb * NCHUNK + chunk) * NS;
#pragma unroll
    for (int s = 0; s < NS; s++)
        pu[(base + s) * DIM + t] = ul[0][s][t] + ul[1][s][t] + ul[2][s][t] + ul[3][s][t];
    if (t < NS)
        pda[base + t] = dl[0][t] + dl[1][t] + dl[2][t] + dl[3][t];
}

// ================= per-iter: finalize -> Aavg (wide: 256 blocks) =============
__global__ void __launch_bounds__(256)
k_fin(const float* __restrict__ pu, const float* __restrict__ pda,
      float* __restrict__ Aavg) {
    int bb = blockIdx.x, s = blockIdx.y, t = threadIdx.x;
    __shared__ float dsh;
    if (t < 64) {
        float a = pda[((size_t)bb * NCHUNK + (t & 31)) * NS + s];
        a += DPPF(a, 0xB1);
        a += DPPF(a, 0x4E);
        a += DPPF(a, 0x124);
        a += DPPF(a, 0x128);
        a = addx16(a);
        if (t == 0) dsh = a;
    }
    const float* src = pu + ((size_t)bb * NCHUNK * NS + s) * DIM + t;
    float acc = 0.f;
#pragma unroll 8
    for (int c = 0; c < NCHUNK; c++) acc += src[(size_t)c * NS * DIM];
    __syncthreads();
    Aavg[((size_t)bb * NS + s) * DIM + t] = acc * __fdividef(1.f, dsh);
}

// ================= per-iter: GRU (wide: 256 blocks, o-tile 32) ===============
__global__ void __launch_bounds__(256)
k_gru(const float* __restrict__ Aavg, const float* __restrict__ slots,
      const float* __restrict__ w2c, const float* __restrict__ whhT,
      const float* __restrict__ b2g, const float* __restrict__ bhh,
      float* __restrict__ news) {
    int bb = blockIdx.x, ot = blockIdx.y, t = threadIdx.x;
    __shared__ float Al[NS][DIM], Sl[NS][DIM];
    for (int idx = t; idx < 512; idx += 256) {
        ((float4*)Al)[idx] = ((const float4*)(Aavg  + (size_t)bb * 2048))[idx];
        ((float4*)Sl)[idx] = ((const float4*)(slots + (size_t)bb * 2048))[idx];
    }
    __syncthreads();
    int r = t >> 5, oc = ot * 32 + (t & 31);
    float ir = 0, iz = 0, in_ = 0, hr = 0, hz = 0, hn = 0;
#pragma unroll 4
    for (int e = 0; e < 256; e++) {
        float w0 = w2c[(size_t)e * 768 + oc];
        float w1 = w2c[(size_t)e * 768 + oc + 256];
        float w2 = w2c[(size_t)e * 768 + oc + 512];
        float u0 = whhT[(size_t)e * 768 + oc];
        float u1 = whhT[(size_t)e * 768 + oc + 256];
        float u2 = whhT[(size_t)e * 768 + oc + 512];
        float a = Al[r][e], h = Sl[r][e];
        ir = fmaf(a, w0, ir); iz = fmaf(a, w1, iz); in_ = fmaf(a, w2, in_);
        hr = fmaf(h, u0, hr); hz = fmaf(h, u1, hz); hn = fmaf(h, u2, hn);
    }
    float gir = ir + b2g[oc], giz = iz + b2g[oc + 256], gin = in_ + b2g[oc + 512];
    float ghr = hr + bhh[oc], ghz = hz + bhh[oc + 256], ghn = hn + bhh[oc + 512];
    float rg = 1.f / (1.f + __expf(-(gir + ghr)));
    float zg = 1.f / (1.f + __expf(-(giz + ghz)));
    float ng = tanhf(fmaf(rg, ghn, gin));
    news[((size_t)bb * NS + r) * DIM + oc] = fmaf(zg, Sl[r][oc] - ng, ng);
}

// ================= per-iter: LN(news) + FF1 (wide: 256 blocks, 64 H-cols) ====
__global__ void __launch_bounds__(256)
k_ff1(const float* __restrict__ news, const float* __restrict__ f1Tp,
      const float* __restrict__ f1bp, float* __restrict__ h1) {
    int bb = blockIdx.x, ht = blockIdx.y, t = threadIdx.x;
    int wave = t >> 6, lane = t & 63;
    __shared__ float Z[NS][DIM];
#pragma unroll
    for (int rr = 0; rr < 2; rr++) {
        int r = wave + rr * 4;
        float4 xv = *(const float4*)&news[((size_t)bb * NS + r) * DIM + lane * 4];
        float S, Q;
        tree2(xv.x + xv.y + xv.z + xv.w,
              xv.x * xv.x + xv.y * xv.y + xv.z * xv.z + xv.w * xv.w, lane, S, Q);
        float m = S * (1.f / DIM);
        float rstd = rsqrtf(Q * (1.f / DIM) - m * m + LN_EPS);
        Z[r][lane * 4 + 0] = (xv.x - m) * rstd;
        Z[r][lane * 4 + 1] = (xv.y - m) * rstd;
        Z[r][lane * 4 + 2] = (xv.z - m) * rstd;
        Z[r][lane * 4 + 3] = (xv.w - m) * rstd;
    }
    __syncthreads();
    int c = ht * 64 + (t & 63), rg = (t >> 6) * 2;
    float a0 = 0.f, a1 = 0.f;
#pragma unroll 4
    for (int e = 0; e < 256; e++) {
        float w = f1Tp[(size_t)e * HID + c];
        a0 = fmaf(Z[rg][e], w, a0);
        a1 = fmaf(Z[rg + 1][e], w, a1);
    }
    float b1 = f1bp[c];
    h1[((size_t)bb * NS + rg) * HID + c]     = fmaxf(a0 + b1, 0.f);
    h1[((size_t)bb * NS + rg + 1) * HID + c] = fmaxf(a1 + b1, 0.f);
}

// ================= per-iter: FF2 + residual (wide: 256 blocks, o-tile 32) ====
__global__ void __launch_bounds__(256)
k_ff2(const float* __restrict__ h1, const float* __restrict__ f2T,
      const float* __restrict__ f2b, const float* __restrict__ news,
      float* __restrict__ slots) {
    int bb = blockIdx.x, ot = blockIdx.y, t = threadIdx.x;
    __shared__ float H[NS][HID];
    for (int idx = t; idx < 1024; idx += 256)
        ((float4*)H)[idx] = ((const float4*)(h1 + (size_t)bb * NS * HID))[idx];
    __syncthreads();
    int r = t >> 5, oc = ot * 32 + (t & 31);
    float acc = 0.f;
#pragma unroll 4
    for (int k = 0; k < HID; k++)
        acc = fmaf(H[r][k], f2T[(size_t)k * 256 + oc], acc);
    slots[((size_t)bb * NS + r) * DIM + oc] =
        news[((size_t)bb * NS + r) * DIM + oc] + acc + f2b[oc];
}

// ================= per-iter: LN(slots) + qk GEMM + c2 (wide) =================
__global__ void __launch_bounds__(256)
k_qk2(const float* __restrict__ slots, const float* __restrict__ Mpp,
      const float* __restrict__ biasp, const float* __restrict__ u2p,
      float* __restrict__ qkw, float* __restrict__ c2b) {
    int bb = blockIdx.x, ot = blockIdx.y, t = threadIdx.x;
    int wave = t >> 6, lane = t & 63;
    __shared__ float Z[NS][DIM];
#pragma unroll
    for (int rr = 0; rr < 2; rr++) {
        int r = wave + rr * 4;
        float4 xv = *(const float4*)&slots[((size_t)bb * NS + r) * DIM + lane * 4];
        float S, Q;
        tree2(xv.x + xv.y + xv.z + xv.w,
              xv.x * xv.x + xv.y * xv.y + xv.z * xv.z + xv.w * xv.w, lane, S, Q);
        float m = S * (1.f / DIM);
        float rstd = rsqrtf(Q * (1.f / DIM) - m * m + LN_EPS);
        Z[r][lane * 4 + 0] = (xv.x - m) * rstd;
        Z[r][lane * 4 + 1] = (xv.y - m) * rstd;
        Z[r][lane * 4 + 2] = (xv.z - m) * rstd;
        Z[r][lane * 4 + 3] = (xv.w - m) * rstd;
    }
    __syncthreads();
    int r = t >> 5, oc = ot * 32 + (t & 31);
    float acc = 0.f;
#pragma unroll 4
    for (int e = 0; e < 256; e++)
        acc = fmaf(Z[r][e], Mpp[(size_t)e * 256 + oc], acc);
    qkw[((size_t)bb * NS + r) * DIM + oc] = acc + biasp[oc];
    if (ot == 0 && t < 64) {
        int s = t >> 3, j = t & 7;
        float a = 0.f;
        for (int e = j * 32; e < j * 32 + 32; e++) a = fmaf(Z[s][e], u2p[e], a);
        a += DPPF(a, 0xB1);
        a += DPPF(a, 0x4E);
        a += DPPF(a, 0x141);
        if (j == 0) c2b[bb * NS + s] = a + biasp[256];
    }
}

extern "C" void kernel_launch(void* const* d_in, const int* in_sizes, int n_in,
                              void* d_out, int out_size, void* d_ws, size_t ws_size,
                              hipStream_t stream) {
    const float* x     = (const float*)d_in[0];
    const float* noise = (const float*)d_in[1];
    const float* mu  = (const float*)d_in[3];
    const float* sg  = (const float*)d_in[4];
    const float* wq  = (const float*)d_in[5];
    const float* bq  = (const float*)d_in[6];
    const float* wk  = (const float*)d_in[7];
    const float* bk  = (const float*)d_in[8];
    const float* wv  = (const float*)d_in[9];
    const float* bv  = (const float*)d_in[10];
    const float* wih = (const float*)d_in[11];
    const float* whh = (const float*)d_in[12];
    const float* bih = (const float*)d_in[13];
    const float* bhh = (const float*)d_in[14];
    const float* f1w = (const float*)d_in[15];
    const float* f1b = (const float*)d_in[16];
    const float* f2w = (const float*)d_in[17];
    const float* f2b = (const float*)d_in[18];
    const float* liw = (const float*)d_in[19];
    const float* lib = (const float*)d_in[20];
    const float* lsw = (const float*)d_in[21];
    const float* lsb = (const float*)d_in[22];
    const float* lfw = (const float*)d_in[23];
    const float* lfb = (const float*)d_in[24];
    float* slots = (float*)d_out;

    __half* xh = (__half*)d_ws;                         // 64 MB
    float* p = (float*)(xh + (size_t)NB * NTOK * DIM);
    float* whhT  = p; p += 256 * 768;
    float* f1Tp  = p; p += 256 * 512;
    float* f2T   = p; p += 512 * 256;
    float* w2c   = p; p += 256 * 768;
    float* Mpp   = p; p += 256 * 256;
    float* u2p   = p; p += 256;
    float* biasp = p; p += 257;
    float* f1bp  = p; p += 512;
    float* b2g   = p; p += 768;
    float* qkw   = p; p += NROWS * 256;
    float* c2b   = p; p += NROWS;
    float* pu    = p; p += (size_t)NB * NCHUNK * NS * DIM;
    float* pda   = p; p += NB * NCHUNK * NS;
    float* Aavg  = p; p += NROWS * 256;
    float* news  = p; p += NROWS * 256;
    float* h1    = p; p += NROWS * 512;

    k_wprep<<<WP_BLKS, 256, 0, stream>>>(
        wq, wk, bk, bq, lsb, lsw, Mpp, u2p, biasp,
        wv, wih, w2c,
        f1w, f1b, lfb, f1bp,
        bih, bv, b2g,
        whh, f2w, lfw, whhT, f1Tp, f2T);
    k_xn<<<XN_TOTAL, 256, 0, stream>>>(
        x, liw, lib, xh,
        noise, mu, sg, slots,
        Mpp, biasp, u2p, qkw, c2b);

    for (int it = 0; it < 3; it++) {
        k_attn<<<dim3(NB, NCHUNK), 256, 0, stream>>>(xh, qkw, c2b, pu, pda);
        k_fin<<<dim3(NB, NS), 256, 0, stream>>>(pu, pda, Aavg);
        k_gru<<<dim3(NB, NS), 256, 0, stream>>>(Aavg, slots, w2c, whhT, b2g, bhh, news);
        k_ff1<<<dim3(NB, NS), 256, 0, stream>>>(news, f1Tp, f1bp, h1);
        k_ff2<<<dim3(NB, NS), 256, 0, stream>>>(h1, f2T, f2b, news, slots);
        if (it < 2)
            k_qk2<<<dim3(NB, NS), 256, 0, stream>>>(slots, Mpp, biasp, u2p, qkw, c2b);
    }
}

// Round 8
// 333.566 us; speedup vs baseline: 1.4452x; 1.4452x over previous
//
#include <hip/hip_runtime.h>
#include <hip/hip_fp16.h>
#include <math.h>

#define NB 32
#define NTOK 4096
#define DIM 256
#define NS 8
#define HID 512
#define NCHUNK 32
#define LN_EPS 1e-5f
#define ATT_EPS 1e-8f
#define SCALE 0.0625f
#define NROWS (NB * NS)   // 256

// ---- cross-lane primitives (VALU-pipe: DPP / permlane) ---------------------
#define DPPF(x, ctrl) __int_as_float(__builtin_amdgcn_update_dpp(0, __float_as_int(x), (ctrl), 0xF, 0xF, true))
// 0xB1 quad_perm xor1, 0x4E quad_perm xor2, 0x141 row_half_mirror (xor7),
// 0x124 row_ror:4, 0x128 row_ror:8

__device__ __forceinline__ float addx16(float c) {
#if __has_builtin(__builtin_amdgcn_permlane16_swap)
    auto r = __builtin_amdgcn_permlane16_swap(__float_as_uint(c), __float_as_uint(c), false, false);
    return __uint_as_float(r[0]) + __uint_as_float(r[1]);
#else
    return c + __shfl_xor(c, 16);
#endif
}
__device__ __forceinline__ float addx32(float c) {
#if __has_builtin(__builtin_amdgcn_permlane32_swap)
    auto r = __builtin_amdgcn_permlane32_swap(__float_as_uint(c), __float_as_uint(c), false, false);
    return __uint_as_float(r[0]) + __uint_as_float(r[1]);
#else
    return c + __shfl_xor(c, 32);
#endif
}

// sum + sumsq over 64 lanes, both results in every lane.
__device__ __forceinline__ void tree2(float v0, float v1, int lane, float& S, float& Q) {
    bool hi = lane & 1;
    float send = hi ? v0 : v1;
    float recv = DPPF(send, 0xB1);
    float a = (hi ? v1 : v0) + recv;
    a += DPPF(a, 0x4E);
    a += DPPF(a, 0x124);
    a += DPPF(a, 0x128);
    a = addx16(a);
    a = addx32(a);
    float other = DPPF(a, 0xB1);
    S = hi ? other : a;
    Q = hi ? a : other;
}

// 8 independent sums over a 32-lane half-wave; lane ends with full half-wave
// sum of slot sig(lane) = (l0<<2)|(l1<<1)|(l0^l1^l2).
__device__ __forceinline__ float tree8h(const float v[8], int lane) {
    bool b0 = lane & 1;
    bool b1 = lane & 2;
    bool bp = ((lane ^ (lane >> 1) ^ (lane >> 2)) & 1);
    float a[4];
#pragma unroll
    for (int j = 0; j < 4; j++) {
        float send = b0 ? v[j] : v[4 + j];
        float recv = DPPF(send, 0xB1);
        a[j] = (b0 ? v[4 + j] : v[j]) + recv;
    }
    float b[2];
#pragma unroll
    for (int j = 0; j < 2; j++) {
        float send = b1 ? a[j] : a[2 + j];
        float recv = DPPF(send, 0x4E);
        b[j] = (b1 ? a[2 + j] : a[j]) + recv;
    }
    float send = bp ? b[0] : b[1];
    float recv = DPPF(send, 0x141);
    float c = (bp ? b[1] : b[0]) + recv;
    c += DPPF(c, 0x128);
    c = addx16(c);
    return c;
}

typedef _Float16 h2v __attribute__((ext_vector_type(2)));
__device__ __forceinline__ float fdot2u(unsigned a, unsigned b, float c) {
#if __has_builtin(__builtin_amdgcn_fdot2)
    return __builtin_amdgcn_fdot2(__builtin_bit_cast(h2v, a), __builtin_bit_cast(h2v, b), c, false);
#else
    __half2 ha = __builtin_bit_cast(__half2, a), hb = __builtin_bit_cast(__half2, b);
    return c + __low2float(ha) * __low2float(hb) + __high2float(ha) * __high2float(hb);
#endif
}
__device__ __forceinline__ unsigned pkh(float a, float b) {
    return __builtin_bit_cast(unsigned, __floats2half2_rn(a, b));
}
__device__ __forceinline__ float2 h2f2(unsigned u) {
    __half2 h = __builtin_bit_cast(__half2, u);
    return float2{__low2float(h), __high2float(h)};
}

// ================= K1: weight prep (role-switched) ===========================
// [0,128)    MppH pair-rows (e-pairs)
// [128]      biasp / u2p / k2
// [129,225)  whhH transpose-pack (96)
// [225,289)  f1H transpose-pack scaled (64)
// [289,353)  f2H transpose-pack (64)
// [353,401)  w2cH (48)
// [401,403)  f1bp (2)
// [403,406)  b2g (3)
#define WP_BIAS  128
#define WP_WHH0  129
#define WP_F1H0  225
#define WP_F2H0  289
#define WP_W2C0  353
#define WP_F1B0  401
#define WP_B2G0  403
#define WP_BLKS  406

__global__ void __launch_bounds__(256)
k_wprep(const float* __restrict__ wq, const float* __restrict__ wk,
        const float* __restrict__ bk, const float* __restrict__ bq,
        const float* __restrict__ lsb, const float* __restrict__ lsw,
        unsigned* __restrict__ MppH, float* __restrict__ u2p, float* __restrict__ biasp,
        const float* __restrict__ wv, const float* __restrict__ wih,
        unsigned* __restrict__ w2cH,
        const float* __restrict__ f1w, const float* __restrict__ f1b,
        const float* __restrict__ lfb, float* __restrict__ f1bp,
        const float* __restrict__ bih, const float* __restrict__ bv,
        float* __restrict__ b2g,
        const float* __restrict__ whh, const float* __restrict__ f2w,
        const float* __restrict__ lfw,
        unsigned* __restrict__ whhH, unsigned* __restrict__ f1H,
        unsigned* __restrict__ f2H) {
    int bid = blockIdx.x, t = threadIdx.x;

    if (bid < WP_BIAS) {                       // ---- MppH: e-pair (2b, 2b+1)
        int b = bid, o = t;
        float a0 = 0.f, a1 = 0.f;
        for (int d = 0; d < 256; d++) {
            float2 wqp = *(const float2*)&wq[(size_t)d * 256 + 2 * b];
            float wkv = wk[(size_t)d * 256 + o];
            a0 = fmaf(wqp.x, wkv, a0);
            a1 = fmaf(wqp.y, wkv, a1);
        }
        MppH[(size_t)b * 256 + o] = pkh(a0 * lsw[2 * b], a1 * lsw[2 * b + 1]);
        return;
    }
    if (bid == WP_BIAS) {                      // ---- biasp / u2p / k2
        int o = t;
        __shared__ float t2l[256], bkl[256], red[4];
        bkl[o] = bk[o];
        float a = bq[o];
        for (int k = 0; k < 256; k++) a = fmaf(wq[(size_t)o * 256 + k], lsb[k], a);
        t2l[o] = a;
        __syncthreads();
        float ab = 0.f, au = 0.f;
        for (int d = 0; d < 256; d++) {
            ab = fmaf(t2l[d], wk[(size_t)d * 256 + o], ab);
            au = fmaf(bkl[d], wq[(size_t)d * 256 + o], au);
        }
        biasp[o] = ab;
        u2p[o] = au * lsw[o];
        float kk = t2l[o] * bkl[o];
        kk += DPPF(kk, 0xB1);
        kk += DPPF(kk, 0x4E);
        kk += DPPF(kk, 0x124);
        kk += DPPF(kk, 0x128);
        kk = addx16(kk);
        kk = addx32(kk);
        if ((t & 63) == 0) red[t >> 6] = kk;
        __syncthreads();
        if (t == 0) biasp[256] = red[0] + red[1] + red[2] + red[3];
        return;
    }
    if (bid < WP_W2C0) {                       // ---- transpose-pack roles
        const float* in; unsigned* out; const float* scl = nullptr;
        int C, OS, r, RT;
        if (bid < WP_F1H0)      { in = whh; out = whhH; C = 256; OS = 768; r = bid - WP_WHH0; RT = 24; }
        else if (bid < WP_F2H0) { in = f1w; out = f1H;  C = 256; OS = 512; r = bid - WP_F1H0; RT = 16; scl = lfw; }
        else                    { in = f2w; out = f2H;  C = 512; OS = 256; r = bid - WP_F2H0; RT = 8; }
        int otl = r % RT, ept = r / RT;        // o-tile of 32 rows, e-tile of 64 cols
        __shared__ float tile[32][65];
#pragma unroll
        for (int i = 0; i < 8; i++) {
            int idx = t + i * 256;
            int row = idx >> 6, col = idx & 63;
            tile[row][col] = in[(size_t)(otl * 32 + row) * C + ept * 64 + col];
        }
        __syncthreads();
#pragma unroll
        for (int i = 0; i < 4; i++) {
            int idx = t + i * 256;
            int epl = idx >> 5, ol = idx & 31;
            float v0 = tile[ol][2 * epl], v1 = tile[ol][2 * epl + 1];
            if (scl) { v0 *= scl[ept * 64 + 2 * epl]; v1 *= scl[ept * 64 + 2 * epl + 1]; }
            out[(size_t)(ept * 32 + epl) * OS + otl * 32 + ol] = pkh(v0, v1);
        }
        return;
    }
    if (bid < WP_F1B0) {                       // ---- w2cH[ep][o]=pk(sum wv[d][2ep..]*wih[o][d])
        int r = bid - WP_W2C0;
        int et = r & 3, ot = r >> 2;           // ep in [et*32,+32), o in [ot*64,+64)
        int ep = et * 32 + (t & 31), og = (t >> 5) * 8;
        float alo[8] = {}, ahi[8] = {};
        for (int d = 0; d < 256; d++) {
            float2 wvp = *(const float2*)&wv[(size_t)d * 256 + 2 * ep];
#pragma unroll
            for (int i = 0; i < 8; i++) {
                float wv_ih = wih[(size_t)(ot * 64 + og + i) * 256 + d];
                alo[i] = fmaf(wvp.x, wv_ih, alo[i]);
                ahi[i] = fmaf(wvp.y, wv_ih, ahi[i]);
            }
        }
#pragma unroll
        for (int i = 0; i < 8; i++)
            w2cH[(size_t)ep * 768 + ot * 64 + og + i] = pkh(alo[i], ahi[i]);
        return;
    }
    if (bid < WP_B2G0) {                       // ---- f1bp
        int h = (bid - WP_F1B0) * 256 + t;
        float a = f1b[h];
        for (int e = 0; e < 256; e++) a = fmaf(f1w[(size_t)h * 256 + e], lfb[e], a);
        f1bp[h] = a;
        return;
    }
    {                                          // ---- b2g
        int o = (bid - WP_B2G0) * 256 + t;
        float a = bih[o];
        for (int d = 0; d < 256; d++) a = fmaf(wih[(size_t)o * 256 + d], bv[d], a);
        b2g[o] = a;
    }
}

// ================= K2: xn -> f16 (row-per-wave, coalesced) ===================
__global__ void __launch_bounds__(256)
k_xn(const float* __restrict__ x, const float* __restrict__ liw,
     const float* __restrict__ lib, __half* __restrict__ xh) {
    int bid = blockIdx.x, t = threadIdx.x;
    int wave = t >> 6, lane = t & 63;
    float4 w4 = *(const float4*)&liw[lane * 4];
    float4 b4 = *(const float4*)&lib[lane * 4];
    size_t rbase = (size_t)bid * 64 + wave;
    float4 cur = *(const float4*)&x[rbase * 256 + lane * 4];
    for (int i = 0; i < 16; i++) {
        float4 nxt;
        if (i < 15) nxt = *(const float4*)&x[(rbase + (size_t)(i + 1) * 4) * 256 + lane * 4];
        float S, Q;
        tree2(cur.x + cur.y + cur.z + cur.w,
              cur.x * cur.x + cur.y * cur.y + cur.z * cur.z + cur.w * cur.w, lane, S, Q);
        float m = S * (1.f / DIM);
        float rstd = rsqrtf(Q * (1.f / DIM) - m * m + LN_EPS);
        uint2 st;
        st.x = pkh((cur.x - m) * rstd * w4.x + b4.x, (cur.y - m) * rstd * w4.y + b4.y);
        st.y = pkh((cur.z - m) * rstd * w4.z + b4.z, (cur.w - m) * rstd * w4.w + b4.w);
        *(uint2*)&xh[(rbase + (size_t)i * 4) * 256 + lane * 4] = st;
        cur = nxt;
    }
}

// ================= K3: slots init + first qk =================================
__global__ void __launch_bounds__(512)
k_iq(const float* __restrict__ noise, const float* __restrict__ mu,
     const float* __restrict__ sg, float* __restrict__ slots,
     const unsigned* __restrict__ MppH, const float* __restrict__ biasp,
     const float* __restrict__ u2p,
     float* __restrict__ qkw, float* __restrict__ c2b) {
    int bb = blockIdx.x, t = threadIdx.x, wave = t >> 6, lane = t & 63;
    __shared__ float S2[NS][DIM], Zl[NS][DIM];
#pragma unroll
    for (int k = 0; k < 4; k++) {
        int idx = k * 512 + t, d = idx & 255;
        float v = mu[d] + sg[d] * noise[(size_t)bb * 2048 + idx];
        S2[idx >> 8][d] = v;
        slots[(size_t)bb * 2048 + idx] = v;
    }
    __syncthreads();
    {
        float4 xv = *(const float4*)&S2[wave][lane * 4];
        float S, Q;
        tree2(xv.x + xv.y + xv.z + xv.w,
              xv.x * xv.x + xv.y * xv.y + xv.z * xv.z + xv.w * xv.w, lane, S, Q);
        float m = S * (1.f / DIM);
        float rstd = rsqrtf(Q * (1.f / DIM) - m * m + LN_EPS);
        Zl[wave][lane * 4 + 0] = (xv.x - m) * rstd;
        Zl[wave][lane * 4 + 1] = (xv.y - m) * rstd;
        Zl[wave][lane * 4 + 2] = (xv.z - m) * rstd;
        Zl[wave][lane * 4 + 3] = (xv.w - m) * rstd;
    }
    __syncthreads();
    int o = t & 255, sg2 = (t >> 8) * 4;
    float acc[4] = {};
    for (int ep = 0; ep < 128; ep++) {
        float2 wf = h2f2(MppH[(size_t)ep * 256 + o]);
#pragma unroll
        for (int i = 0; i < 4; i++) {
            float2 zp = *(const float2*)&Zl[sg2 + i][2 * ep];
            acc[i] = fmaf(zp.x, wf.x, fmaf(zp.y, wf.y, acc[i]));
        }
    }
    float bo = biasp[o];
#pragma unroll
    for (int i = 0; i < 4; i++)
        qkw[(size_t)(bb * NS + sg2 + i) * DIM + o] = acc[i] + bo;
    if (t < 64) {
        int s = t >> 3, j = t & 7;
        float a = 0.f;
        for (int e = j * 32; e < j * 32 + 32; e++) a = fmaf(Zl[s][e], u2p[e], a);
        a += DPPF(a, 0xB1);
        a += DPPF(a, 0x4E);
        a += DPPF(a, 0x141);
        if (j == 0) c2b[bb * NS + s] = a + biasp[256];
    }
}

// ================= per-iter: fused attention =================================
__global__ void __launch_bounds__(256, 3)
k_attn(const __half* __restrict__ xh, const float* __restrict__ qkw,
       const float* __restrict__ c2b,
       float* __restrict__ pu, float* __restrict__ pda) {
    const int bb = blockIdx.x, chunk = blockIdx.y;
    const int t = threadIdx.x, wave = t >> 6, lane = t & 63;
    const int l0 = lane & 1, l1 = (lane >> 1) & 1, l2 = (lane >> 2) & 1;
    const int sig = (l0 << 2) | (l1 << 1) | (l0 ^ l1 ^ l2);
    const int e0 = (lane & 31) * 8;

    unsigned qh[NS][4];
#pragma unroll
    for (int s = 0; s < NS; s++) {
        const float4 a = *(const float4*)&qkw[(size_t)(bb * NS + s) * DIM + e0];
        const float4 b = *(const float4*)&qkw[(size_t)(bb * NS + s) * DIM + e0 + 4];
        qh[s][0] = pkh(a.x, a.y); qh[s][1] = pkh(a.z, a.w);
        qh[s][2] = pkh(b.x, b.y); qh[s][3] = pkh(b.z, b.w);
    }
    const float qbs = c2b[bb * NS + sig] * SCALE;

    float ua[NS][8] = {};
    float da[NS] = {};

    const __half* xp = xh + ((size_t)bb * NTOK + chunk * 128 + wave * 32 + (lane >> 5)) * DIM + e0;
    uint4 nxt = *(const uint4*)xp;
    for (int i = 0; i < 16; i++) {
        uint4 xv = nxt;
        if (i < 15) nxt = *(const uint4*)(xp + (size_t)(i + 1) * 2 * DIM);
        float dp[NS];
#pragma unroll
        for (int s = 0; s < NS; s++)
            dp[s] = fdot2u(qh[s][0], xv.x, fdot2u(qh[s][1], xv.y,
                    fdot2u(qh[s][2], xv.z, fdot2u(qh[s][3], xv.w, 0.f))));
        float ds = tree8h(dp, lane);
        float dv = fmaf(ds, SCALE, qbs);
        float mx = dv;
        mx = fmaxf(mx, DPPF(mx, 0xB1));
        mx = fmaxf(mx, DPPF(mx, 0x4E));
        mx = fmaxf(mx, DPPF(mx, 0x141));
        float e = __expf(dv - mx);
        float sm = e;
        sm += DPPF(sm, 0xB1);
        sm += DPPF(sm, 0x4E);
        sm += DPPF(sm, 0x141);
        float g0 = fmaf(e, __fdividef(1.f, sm), ATT_EPS);
        float g1 = DPPF(g0, 0x141);
        float g2 = DPPF(g0, 0x4E);
        float g3 = DPPF(g1, 0x4E);
        float g4 = DPPF(g0, 0xB1);
        float g5 = DPPF(g1, 0xB1);
        float g6 = DPPF(g2, 0xB1);
        float g7 = DPPF(g3, 0xB1);
        float gth[NS] = {g0, g1, g2, g3, g4, g5, g6, g7};
        __half2 p0 = __builtin_bit_cast(__half2, xv.x);
        __half2 p1 = __builtin_bit_cast(__half2, xv.y);
        __half2 p2 = __builtin_bit_cast(__half2, xv.z);
        __half2 p3 = __builtin_bit_cast(__half2, xv.w);
        float xf[8] = {__low2float(p0), __high2float(p0), __low2float(p1), __high2float(p1),
                       __low2float(p2), __high2float(p2), __low2float(p3), __high2float(p3)};
#pragma unroll
        for (int j = 0; j < NS; j++) {
            float pj = gth[j];
            da[j] += pj;
#pragma unroll
            for (int k = 0; k < 8; k++) ua[j][k] = fmaf(pj, xf[k], ua[j][k]);
        }
    }
#pragma unroll
    for (int j = 0; j < NS; j++) {
        da[j] = addx32(da[j]);
#pragma unroll
        for (int k = 0; k < 8; k++) ua[j][k] = addx32(ua[j][k]);
    }
    __shared__ float ul[4][NS][DIM];
    __shared__ float dl[4][NS];
    const int M8[NS] = {0, 7, 3, 4, 5, 2, 6, 1};
    if (lane < 32) {
#pragma unroll
        for (int j = 0; j < NS; j++) {
            int sj = sig ^ M8[j];
            *(float4*)&ul[wave][sj][e0]     = float4{ua[j][0], ua[j][1], ua[j][2], ua[j][3]};
            *(float4*)&ul[wave][sj][e0 + 4] = float4{ua[j][4], ua[j][5], ua[j][6], ua[j][7]};
        }
    }
    if (lane < 8) {
#pragma unroll
        for (int j = 0; j < NS; j++) dl[wave][sig ^ M8[j]] = da[j];
    }
    __syncthreads();
    size_t base = ((size_t)bb * NCHUNK + chunk) * NS;
#pragma unroll
    for (int s = 0; s < NS; s++)
        pu[(base + s) * DIM + t] = ul[0][s][t] + ul[1][s][t] + ul[2][s][t] + ul[3][s][t];
    if (t < NS)
        pda[base + t] = dl[0][t] + dl[1][t] + dl[2][t] + dl[3][t];
}

// ================= per-iter: finalize -> Aavg ================================
__global__ void __launch_bounds__(256)
k_fin(const float* __restrict__ pu, const float* __restrict__ pda,
      float* __restrict__ Aavg) {
    int bb = blockIdx.x, s = blockIdx.y, t = threadIdx.x;
    __shared__ float dsh;
    if (t < 64) {
        float a = pda[((size_t)bb * NCHUNK + (t & 31)) * NS + s];
        a += DPPF(a, 0xB1);
        a += DPPF(a, 0x4E);
        a += DPPF(a, 0x124);
        a += DPPF(a, 0x128);
        a = addx16(a);
        if (t == 0) dsh = a;
    }
    const float* src = pu + ((size_t)bb * NCHUNK * NS + s) * DIM + t;
    float acc = 0.f;
#pragma unroll 8
    for (int c = 0; c < NCHUNK; c++) acc += src[(size_t)c * NS * DIM];
    __syncthreads();
    Aavg[((size_t)bb * NS + s) * DIM + t] = acc * __fdividef(1.f, dsh);
}

// ================= per-iter: GRU (split-K, 512 thr, grid 32x8) ===============
__global__ void __launch_bounds__(512)
k_gru(const float* __restrict__ Aavg, const float* __restrict__ slots,
      const unsigned* __restrict__ w2cH, const unsigned* __restrict__ whhH,
      const float* __restrict__ b2g, const float* __restrict__ bhh,
      float* __restrict__ news) {
    int bb = blockIdx.x, ot = blockIdx.y, t = threadIdx.x;
    __shared__ float Al[NS][DIM], Sl[NS][DIM];
    __shared__ float pp[256][6];
#pragma unroll
    for (int k = 0; k < 1; k++) {}
    for (int idx = t; idx < 512; idx += 512) {
        ((float4*)Al)[idx] = ((const float4*)(Aavg  + (size_t)bb * 2048))[idx];
        ((float4*)Sl)[idx] = ((const float4*)(slots + (size_t)bb * 2048))[idx];
    }
    __syncthreads();
    int oc = ot * 32 + (t & 31);
    int r = (t >> 5) & 7;
    int half = t >> 8;
    float ir = 0, iz = 0, in_ = 0, hr = 0, hz = 0, hn = 0;
    int ep0 = half * 64;
#pragma unroll 2
    for (int epi = 0; epi < 64; epi++) {
        int ep = ep0 + epi;
        float2 w0 = h2f2(w2cH[(size_t)ep * 768 + oc]);
        float2 w1 = h2f2(w2cH[(size_t)ep * 768 + oc + 256]);
        float2 w2 = h2f2(w2cH[(size_t)ep * 768 + oc + 512]);
        float2 u0 = h2f2(whhH[(size_t)ep * 768 + oc]);
        float2 u1 = h2f2(whhH[(size_t)ep * 768 + oc + 256]);
        float2 u2 = h2f2(whhH[(size_t)ep * 768 + oc + 512]);
        float2 ap = *(const float2*)&Al[r][2 * ep];
        float2 hp = *(const float2*)&Sl[r][2 * ep];
        ir = fmaf(ap.x, w0.x, fmaf(ap.y, w0.y, ir));
        iz = fmaf(ap.x, w1.x, fmaf(ap.y, w1.y, iz));
        in_ = fmaf(ap.x, w2.x, fmaf(ap.y, w2.y, in_));
        hr = fmaf(hp.x, u0.x, fmaf(hp.y, u0.y, hr));
        hz = fmaf(hp.x, u1.x, fmaf(hp.y, u1.y, hz));
        hn = fmaf(hp.x, u2.x, fmaf(hp.y, u2.y, hn));
    }
    int tid = t & 255;
    if (half) {
        pp[tid][0] = ir; pp[tid][1] = iz; pp[tid][2] = in_;
        pp[tid][3] = hr; pp[tid][4] = hz; pp[tid][5] = hn;
    }
    __syncthreads();
    if (!half) {
        ir += pp[tid][0]; iz += pp[tid][1]; in_ += pp[tid][2];
        hr += pp[tid][3]; hz += pp[tid][4]; hn += pp[tid][5];
        float gir = ir + b2g[oc], giz = iz + b2g[oc + 256], gin = in_ + b2g[oc + 512];
        float ghr = hr + bhh[oc], ghz = hz + bhh[oc + 256], ghn = hn + bhh[oc + 512];
        float rg = 1.f / (1.f + __expf(-(gir + ghr)));
        float zg = 1.f / (1.f + __expf(-(giz + ghz)));
        float ng = tanhf(fmaf(rg, ghn, gin));
        news[((size_t)bb * NS + r) * DIM + oc] = fmaf(zg, Sl[r][oc] - ng, ng);
    }
}

// ================= per-iter: LN(news) + FF1 (512 thr, grid 32x8) =============
__global__ void __launch_bounds__(512)
k_ff1(const float* __restrict__ news, const unsigned* __restrict__ f1H,
      const float* __restrict__ f1bp, float* __restrict__ h1) {
    int bb = blockIdx.x, ht = blockIdx.y, t = threadIdx.x;
    int wave = t >> 6, lane = t & 63;
    __shared__ float Z[NS][DIM];
    {
        float4 xv = *(const float4*)&news[((size_t)bb * NS + wave) * DIM + lane * 4];
        float S, Q;
        tree2(xv.x + xv.y + xv.z + xv.w,
              xv.x * xv.x + xv.y * xv.y + xv.z * xv.z + xv.w * xv.w, lane, S, Q);
        float m = S * (1.f / DIM);
        float rstd = rsqrtf(Q * (1.f / DIM) - m * m + LN_EPS);
        Z[wave][lane * 4 + 0] = (xv.x - m) * rstd;
        Z[wave][lane * 4 + 1] = (xv.y - m) * rstd;
        Z[wave][lane * 4 + 2] = (xv.z - m) * rstd;
        Z[wave][lane * 4 + 3] = (xv.w - m) * rstd;
    }
    __syncthreads();
    int c = ht * 64 + (t & 63), rq = t >> 6;
    float acc = 0.f;
#pragma unroll 2
    for (int ep = 0; ep < 128; ep++) {
        float2 wf = h2f2(f1H[(size_t)ep * HID + c]);
        float2 zp = *(const float2*)&Z[rq][2 * ep];
        acc = fmaf(zp.x, wf.x, fmaf(zp.y, wf.y, acc));
    }
    h1[((size_t)bb * NS + rq) * HID + c] = fmaxf(acc + f1bp[c], 0.f);
}

// ================= per-iter: FF2 + residual (split-K, 512 thr, 32x8) =========
__global__ void __launch_bounds__(512)
k_ff2(const float* __restrict__ h1, const unsigned* __restrict__ f2H,
      const float* __restrict__ f2b, const float* __restrict__ news,
      float* __restrict__ slots) {
    int bb = blockIdx.x, ot = blockIdx.y, t = threadIdx.x;
    __shared__ float H[NS][HID];
    __shared__ float pp2[256];
    for (int idx = t; idx < 1024; idx += 512)
        ((float4*)H)[idx] = ((const float4*)(h1 + (size_t)bb * NS * HID))[idx];
    __syncthreads();
    int oc = ot * 32 + (t & 31);
    int r = (t >> 5) & 7;
    int half = t >> 8;
    float acc = 0.f;
    int kp0 = half * 128;
#pragma unroll 2
    for (int kpi = 0; kpi < 128; kpi++) {
        int kp = kp0 + kpi;
        float2 wf = h2f2(f2H[(size_t)kp * 256 + oc]);
        float2 hp = *(const float2*)&H[r][2 * kp];
        acc = fmaf(hp.x, wf.x, fmaf(hp.y, wf.y, acc));
    }
    int tid = t & 255;
    if (half) pp2[tid] = acc;
    __syncthreads();
    if (!half) {
        slots[((size_t)bb * NS + r) * DIM + oc] =
            news[((size_t)bb * NS + r) * DIM + oc] + acc + pp2[tid] + f2b[oc];
    }
}

// ================= per-iter: LN(slots) + qk + c2 (split-K, 512 thr, 32x8) ====
__global__ void __launch_bounds__(512)
k_qk2(const float* __restrict__ slots, const unsigned* __restrict__ MppH,
      const float* __restrict__ biasp, const float* __restrict__ u2p,
      float* __restrict__ qkw, float* __restrict__ c2b) {
    int bb = blockIdx.x, ot = blockIdx.y, t = threadIdx.x;
    int wave = t >> 6, lane = t & 63;
    __shared__ float Z[NS][DIM];
    __shared__ float pp2[256];
    {
        float4 xv = *(const float4*)&slots[((size_t)bb * NS + wave) * DIM + lane * 4];
        float S, Q;
        tree2(xv.x + xv.y + xv.z + xv.w,
              xv.x * xv.x + xv.y * xv.y + xv.z * xv.z + xv.w * xv.w, lane, S, Q);
        float m = S * (1.f / DIM);
        float rstd = rsqrtf(Q * (1.f / DIM) - m * m + LN_EPS);
        Z[wave][lane * 4 + 0] = (xv.x - m) * rstd;
        Z[wave][lane * 4 + 1] = (xv.y - m) * rstd;
        Z[wave][lane * 4 + 2] = (xv.z - m) * rstd;
        Z[wave][lane * 4 + 3] = (xv.w - m) * rstd;
    }
    __syncthreads();
    int oc = ot * 32 + (t & 31);
    int r = (t >> 5) & 7;
    int half = t >> 8;
    float acc = 0.f;
    int ep0 = half * 64;
#pragma unroll 2
    for (int epi = 0; epi < 64; epi++) {
        int ep = ep0 + epi;
        float2 wf = h2f2(MppH[(size_t)ep * 256 + oc]);
        float2 zp = *(const float2*)&Z[r][2 * ep];
        acc = fmaf(zp.x, wf.x, fmaf(zp.y, wf.y, acc));
    }
    int tid = t & 255;
    if (half) pp2[tid] = acc;
    __syncthreads();
    if (!half)
        qkw[((size_t)bb * NS + r) * DIM + oc] = acc + pp2[tid] + biasp[oc];
    if (ot == 0 && t < 64) {
        int s = t >> 3, j = t & 7;
        float a = 0.f;
        for (int e = j * 32; e < j * 32 + 32; e++) a = fmaf(Z[s][e], u2p[e], a);
        a += DPPF(a, 0xB1);
        a += DPPF(a, 0x4E);
        a += DPPF(a, 0x141);
        if (j == 0) c2b[bb * NS + s] = a + biasp[256];
    }
}

extern "C" void kernel_launch(void* const* d_in, const int* in_sizes, int n_in,
                              void* d_out, int out_size, void* d_ws, size_t ws_size,
                              hipStream_t stream) {
    const float* x     = (const float*)d_in[0];
    const float* noise = (const float*)d_in[1];
    const float* mu  = (const float*)d_in[3];
    const float* sg  = (const float*)d_in[4];
    const float* wq  = (const float*)d_in[5];
    const float* bq  = (const float*)d_in[6];
    const float* wk  = (const float*)d_in[7];
    const float* bk  = (const float*)d_in[8];
    const float* wv  = (const float*)d_in[9];
    const float* bv  = (const float*)d_in[10];
    const float* wih = (const float*)d_in[11];
    const float* whh = (const float*)d_in[12];
    const float* bih = (const float*)d_in[13];
    const float* bhh = (const float*)d_in[14];
    const float* f1w = (const float*)d_in[15];
    const float* f1b = (const float*)d_in[16];
    const float* f2w = (const float*)d_in[17];
    const float* f2b = (const float*)d_in[18];
    const float* liw = (const float*)d_in[19];
    const float* lib = (const float*)d_in[20];
    const float* lsw = (const float*)d_in[21];
    const float* lsb = (const float*)d_in[22];
    const float* lfw = (const float*)d_in[23];
    const float* lfb = (const float*)d_in[24];
    float* slots = (float*)d_out;

    __half* xh = (__half*)d_ws;                         // 64 MB
    float* p = (float*)(xh + (size_t)NB * NTOK * DIM);
    unsigned* MppH = (unsigned*)p; p += 128 * 256;
    unsigned* w2cH = (unsigned*)p; p += 128 * 768;
    unsigned* whhH = (unsigned*)p; p += 128 * 768;
    unsigned* f1H  = (unsigned*)p; p += 128 * 512;
    unsigned* f2H  = (unsigned*)p; p += 256 * 256;
    float* u2p   = p; p += 256;
    float* biasp = p; p += 257;
    float* f1bp  = p; p += 512;
    float* b2g   = p; p += 768;
    float* qkw   = p; p += NROWS * 256;
    float* c2b   = p; p += NROWS;
    float* pu    = p; p += (size_t)NB * NCHUNK * NS * DIM;
    float* pda   = p; p += NB * NCHUNK * NS;
    float* Aavg  = p; p += NROWS * 256;
    float* news  = p; p += NROWS * 256;
    float* h1    = p; p += NROWS * 512;

    k_wprep<<<WP_BLKS, 256, 0, stream>>>(
        wq, wk, bk, bq, lsb, lsw, MppH, u2p, biasp,
        wv, wih, w2cH,
        f1w, f1b, lfb, f1bp,
        bih, bv, b2g,
        whh, f2w, lfw, whhH, f1H, f2H);
    k_xn<<<2048, 256, 0, stream>>>(x, liw, lib, xh);
    k_iq<<<NB, 512, 0, stream>>>(noise, mu, sg, slots, MppH, biasp, u2p, qkw, c2b);

    for (int it = 0; it < 3; it++) {
        k_attn<<<dim3(NB, NCHUNK), 256, 0, stream>>>(xh, qkw, c2b, pu, pda);
        k_fin<<<dim3(NB, NS), 256, 0, stream>>>(pu, pda, Aavg);
        k_gru<<<dim3(NB, NS), 512, 0, stream>>>(Aavg, slots, w2cH, whhH, b2g, bhh, news);
        k_ff1<<<dim3(NB, NS), 512, 0, stream>>>(news, f1H, f1bp, h1);
        k_ff2<<<dim3(NB, NS), 512, 0, stream>>>(h1, f2H, f2b, news, slots);
        if (it < 2)
            k_qk2<<<dim3(NB, NS), 512, 0, stream>>>(slots, MppH, biasp, u2p, qkw, c2b);
    }
}

// Round 9
// 229.952 us; speedup vs baseline: 2.0965x; 1.4506x over previous
//
#include <hip/hip_runtime.h>
#include <hip/hip_fp16.h>
#include <math.h>

#define NB 32
#define NTOK 4096
#define DIM 256
#define NS 8
#define HID 512
#define NCHUNK 32
#define LN_EPS 1e-5f
#define ATT_EPS 1e-8f
#define SCALE 0.0625f
#define NROWS (NB * NS)   // 256

// ---- cross-lane primitives (VALU-pipe: DPP / permlane) ---------------------
#define DPPF(x, ctrl) __int_as_float(__builtin_amdgcn_update_dpp(0, __float_as_int(x), (ctrl), 0xF, 0xF, true))
// 0xB1 quad_perm xor1, 0x4E quad_perm xor2, 0x141 row_half_mirror (xor7),
// 0x124 row_ror:4, 0x128 row_ror:8

__device__ __forceinline__ float addx16(float c) {
#if __has_builtin(__builtin_amdgcn_permlane16_swap)
    auto r = __builtin_amdgcn_permlane16_swap(__float_as_uint(c), __float_as_uint(c), false, false);
    return __uint_as_float(r[0]) + __uint_as_float(r[1]);
#else
    return c + __shfl_xor(c, 16);
#endif
}
__device__ __forceinline__ float addx32(float c) {
#if __has_builtin(__builtin_amdgcn_permlane32_swap)
    auto r = __builtin_amdgcn_permlane32_swap(__float_as_uint(c), __float_as_uint(c), false, false);
    return __uint_as_float(r[0]) + __uint_as_float(r[1]);
#else
    return c + __shfl_xor(c, 32);
#endif
}

// sum + sumsq over 64 lanes, both results in every lane.
__device__ __forceinline__ void tree2(float v0, float v1, int lane, float& S, float& Q) {
    bool hi = lane & 1;
    float send = hi ? v0 : v1;
    float recv = DPPF(send, 0xB1);
    float a = (hi ? v1 : v0) + recv;
    a += DPPF(a, 0x4E);
    a += DPPF(a, 0x124);
    a += DPPF(a, 0x128);
    a = addx16(a);
    a = addx32(a);
    float other = DPPF(a, 0xB1);
    S = hi ? other : a;
    Q = hi ? a : other;
}

// 8 independent sums over a 32-lane half-wave; lane ends with full half-wave
// sum of slot sig(lane) = (l0<<2)|(l1<<1)|(l0^l1^l2).
__device__ __forceinline__ float tree8h(const float v[8], int lane) {
    bool b0 = lane & 1;
    bool b1 = lane & 2;
    bool bp = ((lane ^ (lane >> 1) ^ (lane >> 2)) & 1);
    float a[4];
#pragma unroll
    for (int j = 0; j < 4; j++) {
        float send = b0 ? v[j] : v[4 + j];
        float recv = DPPF(send, 0xB1);
        a[j] = (b0 ? v[4 + j] : v[j]) + recv;
    }
    float b[2];
#pragma unroll
    for (int j = 0; j < 2; j++) {
        float send = b1 ? a[j] : a[2 + j];
        float recv = DPPF(send, 0x4E);
        b[j] = (b1 ? a[2 + j] : a[j]) + recv;
    }
    float send = bp ? b[0] : b[1];
    float recv = DPPF(send, 0x141);
    float c = (bp ? b[1] : b[0]) + recv;
    c += DPPF(c, 0x128);
    c = addx16(c);
    return c;
}

typedef _Float16 h2v __attribute__((ext_vector_type(2)));
__device__ __forceinline__ float fdot2u(unsigned a, unsigned b, float c) {
#if __has_builtin(__builtin_amdgcn_fdot2)
    return __builtin_amdgcn_fdot2(__builtin_bit_cast(h2v, a), __builtin_bit_cast(h2v, b), c, false);
#else
    __half2 ha = __builtin_bit_cast(__half2, a), hb = __builtin_bit_cast(__half2, b);
    return c + __low2float(ha) * __low2float(hb) + __high2float(ha) * __high2float(hb);
#endif
}
__device__ __forceinline__ unsigned pkh(float a, float b) {
    return __builtin_bit_cast(unsigned, __floats2half2_rn(a, b));
}
__device__ __forceinline__ float2 h2f2(unsigned u) {
    __half2 h = __builtin_bit_cast(__half2, u);
    return float2{__low2float(h), __high2float(h)};
}

// ================= K1: weight prep (role-switched) ===========================
#define WP_BIAS  128
#define WP_WHH0  129
#define WP_F1H0  225
#define WP_F2H0  289
#define WP_W2C0  353
#define WP_F1B0  401
#define WP_B2G0  403
#define WP_BLKS  406

__global__ void __launch_bounds__(256)
k_wprep(const float* __restrict__ wq, const float* __restrict__ wk,
        const float* __restrict__ bk, const float* __restrict__ bq,
        const float* __restrict__ lsb, const float* __restrict__ lsw,
        unsigned* __restrict__ MppH, float* __restrict__ u2p, float* __restrict__ biasp,
        const float* __restrict__ wv, const float* __restrict__ wih,
        unsigned* __restrict__ w2cH,
        const float* __restrict__ f1w, const float* __restrict__ f1b,
        const float* __restrict__ lfb, float* __restrict__ f1bp,
        const float* __restrict__ bih, const float* __restrict__ bv,
        float* __restrict__ b2g,
        const float* __restrict__ whh, const float* __restrict__ f2w,
        const float* __restrict__ lfw,
        unsigned* __restrict__ whhH, unsigned* __restrict__ f1H,
        unsigned* __restrict__ f2H) {
    int bid = blockIdx.x, t = threadIdx.x;

    if (bid < WP_BIAS) {                       // ---- MppH: e-pair (2b, 2b+1)
        int b = bid, o = t;
        float a0 = 0.f, a1 = 0.f;
        for (int d = 0; d < 256; d++) {
            float2 wqp = *(const float2*)&wq[(size_t)d * 256 + 2 * b];
            float wkv = wk[(size_t)d * 256 + o];
            a0 = fmaf(wqp.x, wkv, a0);
            a1 = fmaf(wqp.y, wkv, a1);
        }
        MppH[(size_t)b * 256 + o] = pkh(a0 * lsw[2 * b], a1 * lsw[2 * b + 1]);
        return;
    }
    if (bid == WP_BIAS) {                      // ---- biasp / u2p / k2
        int o = t;
        __shared__ float t2l[256], bkl[256], red[4];
        bkl[o] = bk[o];
        float a = bq[o];
        for (int k = 0; k < 256; k++) a = fmaf(wq[(size_t)o * 256 + k], lsb[k], a);
        t2l[o] = a;
        __syncthreads();
        float ab = 0.f, au = 0.f;
        for (int d = 0; d < 256; d++) {
            ab = fmaf(t2l[d], wk[(size_t)d * 256 + o], ab);
            au = fmaf(bkl[d], wq[(size_t)d * 256 + o], au);
        }
        biasp[o] = ab;
        u2p[o] = au * lsw[o];
        float kk = t2l[o] * bkl[o];
        kk += DPPF(kk, 0xB1);
        kk += DPPF(kk, 0x4E);
        kk += DPPF(kk, 0x124);
        kk += DPPF(kk, 0x128);
        kk = addx16(kk);
        kk = addx32(kk);
        if ((t & 63) == 0) red[t >> 6] = kk;
        __syncthreads();
        if (t == 0) biasp[256] = red[0] + red[1] + red[2] + red[3];
        return;
    }
    if (bid < WP_W2C0) {                       // ---- transpose-pack roles
        const float* in; unsigned* out; const float* scl = nullptr;
        int C, OS, r, RT;
        if (bid < WP_F1H0)      { in = whh; out = whhH; C = 256; OS = 768; r = bid - WP_WHH0; RT = 24; }
        else if (bid < WP_F2H0) { in = f1w; out = f1H;  C = 256; OS = 512; r = bid - WP_F1H0; RT = 16; scl = lfw; }
        else                    { in = f2w; out = f2H;  C = 512; OS = 256; r = bid - WP_F2H0; RT = 8; }
        int otl = r % RT, ept = r / RT;
        __shared__ float tile[32][65];
#pragma unroll
        for (int i = 0; i < 8; i++) {
            int idx = t + i * 256;
            int row = idx >> 6, col = idx & 63;
            tile[row][col] = in[(size_t)(otl * 32 + row) * C + ept * 64 + col];
        }
        __syncthreads();
#pragma unroll
        for (int i = 0; i < 4; i++) {
            int idx = t + i * 256;
            int epl = idx >> 5, ol = idx & 31;
            float v0 = tile[ol][2 * epl], v1 = tile[ol][2 * epl + 1];
            if (scl) { v0 *= scl[ept * 64 + 2 * epl]; v1 *= scl[ept * 64 + 2 * epl + 1]; }
            out[(size_t)(ept * 32 + epl) * OS + otl * 32 + ol] = pkh(v0, v1);
        }
        return;
    }
    if (bid < WP_F1B0) {                       // ---- w2cH
        int r = bid - WP_W2C0;
        int et = r & 3, ot = r >> 2;
        int ep = et * 32 + (t & 31), og = (t >> 5) * 8;
        float alo[8] = {}, ahi[8] = {};
        for (int d = 0; d < 256; d++) {
            float2 wvp = *(const float2*)&wv[(size_t)d * 256 + 2 * ep];
#pragma unroll
            for (int i = 0; i < 8; i++) {
                float wv_ih = wih[(size_t)(ot * 64 + og + i) * 256 + d];
                alo[i] = fmaf(wvp.x, wv_ih, alo[i]);
                ahi[i] = fmaf(wvp.y, wv_ih, ahi[i]);
            }
        }
#pragma unroll
        for (int i = 0; i < 8; i++)
            w2cH[(size_t)ep * 768 + ot * 64 + og + i] = pkh(alo[i], ahi[i]);
        return;
    }
    if (bid < WP_B2G0) {                       // ---- f1bp
        int h = (bid - WP_F1B0) * 256 + t;
        float a = f1b[h];
        for (int e = 0; e < 256; e++) a = fmaf(f1w[(size_t)h * 256 + e], lfb[e], a);
        f1bp[h] = a;
        return;
    }
    {                                          // ---- b2g
        int o = (bid - WP_B2G0) * 256 + t;
        float a = bih[o];
        for (int d = 0; d < 256; d++) a = fmaf(wih[(size_t)o * 256 + d], bv[d], a);
        b2g[o] = a;
    }
}

// ================= K2: xn -> f16 (row-per-wave, coalesced) ===================
__global__ void __launch_bounds__(256)
k_xn(const float* __restrict__ x, const float* __restrict__ liw,
     const float* __restrict__ lib, __half* __restrict__ xh) {
    int bid = blockIdx.x, t = threadIdx.x;
    int wave = t >> 6, lane = t & 63;
    float4 w4 = *(const float4*)&liw[lane * 4];
    float4 b4 = *(const float4*)&lib[lane * 4];
    size_t rbase = (size_t)bid * 64 + wave;
    float4 cur = *(const float4*)&x[rbase * 256 + lane * 4];
    for (int i = 0; i < 16; i++) {
        float4 nxt;
        if (i < 15) nxt = *(const float4*)&x[(rbase + (size_t)(i + 1) * 4) * 256 + lane * 4];
        float S, Q;
        tree2(cur.x + cur.y + cur.z + cur.w,
              cur.x * cur.x + cur.y * cur.y + cur.z * cur.z + cur.w * cur.w, lane, S, Q);
        float m = S * (1.f / DIM);
        float rstd = rsqrtf(Q * (1.f / DIM) - m * m + LN_EPS);
        uint2 st;
        st.x = pkh((cur.x - m) * rstd * w4.x + b4.x, (cur.y - m) * rstd * w4.y + b4.y);
        st.y = pkh((cur.z - m) * rstd * w4.z + b4.z, (cur.w - m) * rstd * w4.w + b4.w);
        *(uint2*)&xh[(rbase + (size_t)i * 4) * 256 + lane * 4] = st;
        cur = nxt;
    }
}

// ================= K3: slots init + first qk =================================
__global__ void __launch_bounds__(512)
k_iq(const float* __restrict__ noise, const float* __restrict__ mu,
     const float* __restrict__ sg, float* __restrict__ slots,
     const unsigned* __restrict__ MppH, const float* __restrict__ biasp,
     const float* __restrict__ u2p,
     float* __restrict__ qkw, float* __restrict__ c2b) {
    int bb = blockIdx.x, t = threadIdx.x, wave = t >> 6, lane = t & 63;
    __shared__ float S2[NS][DIM], Zl[NS][DIM];
#pragma unroll
    for (int k = 0; k < 4; k++) {
        int idx = k * 512 + t, d = idx & 255;
        float v = mu[d] + sg[d] * noise[(size_t)bb * 2048 + idx];
        S2[idx >> 8][d] = v;
        slots[(size_t)bb * 2048 + idx] = v;
    }
    __syncthreads();
    {
        float4 xv = *(const float4*)&S2[wave][lane * 4];
        float S, Q;
        tree2(xv.x + xv.y + xv.z + xv.w,
              xv.x * xv.x + xv.y * xv.y + xv.z * xv.z + xv.w * xv.w, lane, S, Q);
        float m = S * (1.f / DIM);
        float rstd = rsqrtf(Q * (1.f / DIM) - m * m + LN_EPS);
        Zl[wave][lane * 4 + 0] = (xv.x - m) * rstd;
        Zl[wave][lane * 4 + 1] = (xv.y - m) * rstd;
        Zl[wave][lane * 4 + 2] = (xv.z - m) * rstd;
        Zl[wave][lane * 4 + 3] = (xv.w - m) * rstd;
    }
    __syncthreads();
    int o = t & 255, sg2 = (t >> 8) * 4;
    float acc[4] = {};
    for (int ep = 0; ep < 128; ep++) {
        float2 wf = h2f2(MppH[(size_t)ep * 256 + o]);
#pragma unroll
        for (int i = 0; i < 4; i++) {
            float2 zp = *(const float2*)&Zl[sg2 + i][2 * ep];
            acc[i] = fmaf(zp.x, wf.x, fmaf(zp.y, wf.y, acc[i]));
        }
    }
    float bo = biasp[o];
#pragma unroll
    for (int i = 0; i < 4; i++)
        qkw[(size_t)(bb * NS + sg2 + i) * DIM + o] = acc[i] + bo;
    if (t < 64) {
        int s = t >> 3, j = t & 7;
        float a = 0.f;
        for (int e = j * 32; e < j * 32 + 32; e++) a = fmaf(Zl[s][e], u2p[e], a);
        a += DPPF(a, 0xB1);
        a += DPPF(a, 0x4E);
        a += DPPF(a, 0x141);
        if (j == 0) c2b[bb * NS + s] = a + biasp[256];
    }
}

// ================= per-iter: fused attention =================================
__global__ void __launch_bounds__(256, 3)
k_attn(const __half* __restrict__ xh, const float* __restrict__ qkw,
       const float* __restrict__ c2b,
       float* __restrict__ pu, float* __restrict__ pda) {
    const int bb = blockIdx.x, chunk = blockIdx.y;
    const int t = threadIdx.x, wave = t >> 6, lane = t & 63;
    const int l0 = lane & 1, l1 = (lane >> 1) & 1, l2 = (lane >> 2) & 1;
    const int sig = (l0 << 2) | (l1 << 1) | (l0 ^ l1 ^ l2);
    const int e0 = (lane & 31) * 8;

    unsigned qh[NS][4];
#pragma unroll
    for (int s = 0; s < NS; s++) {
        const float4 a = *(const float4*)&qkw[(size_t)(bb * NS + s) * DIM + e0];
        const float4 b = *(const float4*)&qkw[(size_t)(bb * NS + s) * DIM + e0 + 4];
        qh[s][0] = pkh(a.x, a.y); qh[s][1] = pkh(a.z, a.w);
        qh[s][2] = pkh(b.x, b.y); qh[s][3] = pkh(b.z, b.w);
    }
    const float qbs = c2b[bb * NS + sig] * SCALE;

    float ua[NS][8] = {};
    float da[NS] = {};

    const __half* xp = xh + ((size_t)bb * NTOK + chunk * 128 + wave * 32 + (lane >> 5)) * DIM + e0;
    uint4 nxt = *(const uint4*)xp;
    for (int i = 0; i < 16; i++) {
        uint4 xv = nxt;
        if (i < 15) nxt = *(const uint4*)(xp + (size_t)(i + 1) * 2 * DIM);
        float dp[NS];
#pragma unroll
        for (int s = 0; s < NS; s++)
            dp[s] = fdot2u(qh[s][0], xv.x, fdot2u(qh[s][1], xv.y,
                    fdot2u(qh[s][2], xv.z, fdot2u(qh[s][3], xv.w, 0.f))));
        float ds = tree8h(dp, lane);
        float dv = fmaf(ds, SCALE, qbs);
        float mx = dv;
        mx = fmaxf(mx, DPPF(mx, 0xB1));
        mx = fmaxf(mx, DPPF(mx, 0x4E));
        mx = fmaxf(mx, DPPF(mx, 0x141));
        float e = __expf(dv - mx);
        float sm = e;
        sm += DPPF(sm, 0xB1);
        sm += DPPF(sm, 0x4E);
        sm += DPPF(sm, 0x141);
        float g0 = fmaf(e, __fdividef(1.f, sm), ATT_EPS);
        float g1 = DPPF(g0, 0x141);
        float g2 = DPPF(g0, 0x4E);
        float g3 = DPPF(g1, 0x4E);
        float g4 = DPPF(g0, 0xB1);
        float g5 = DPPF(g1, 0xB1);
        float g6 = DPPF(g2, 0xB1);
        float g7 = DPPF(g3, 0xB1);
        float gth[NS] = {g0, g1, g2, g3, g4, g5, g6, g7};
        __half2 p0 = __builtin_bit_cast(__half2, xv.x);
        __half2 p1 = __builtin_bit_cast(__half2, xv.y);
        __half2 p2 = __builtin_bit_cast(__half2, xv.z);
        __half2 p3 = __builtin_bit_cast(__half2, xv.w);
        float xf[8] = {__low2float(p0), __high2float(p0), __low2float(p1), __high2float(p1),
                       __low2float(p2), __high2float(p2), __low2float(p3), __high2float(p3)};
#pragma unroll
        for (int j = 0; j < NS; j++) {
            float pj = gth[j];
            da[j] += pj;
#pragma unroll
            for (int k = 0; k < 8; k++) ua[j][k] = fmaf(pj, xf[k], ua[j][k]);
        }
    }
#pragma unroll
    for (int j = 0; j < NS; j++) {
        da[j] = addx32(da[j]);
#pragma unroll
        for (int k = 0; k < 8; k++) ua[j][k] = addx32(ua[j][k]);
    }
    __shared__ float ul[4][NS][DIM];
    __shared__ float dl[4][NS];
    const int M8[NS] = {0, 7, 3, 4, 5, 2, 6, 1};
    if (lane < 32) {
#pragma unroll
        for (int j = 0; j < NS; j++) {
            int sj = sig ^ M8[j];
            *(float4*)&ul[wave][sj][e0]     = float4{ua[j][0], ua[j][1], ua[j][2], ua[j][3]};
            *(float4*)&ul[wave][sj][e0 + 4] = float4{ua[j][4], ua[j][5], ua[j][6], ua[j][7]};
        }
    }
    if (lane < 8) {
#pragma unroll
        for (int j = 0; j < NS; j++) dl[wave][sig ^ M8[j]] = da[j];
    }
    __syncthreads();
    size_t base = ((size_t)bb * NCHUNK + chunk) * NS;
#pragma unroll
    for (int s = 0; s < NS; s++)
        pu[(base + s) * DIM + t] = ul[0][s][t] + ul[1][s][t] + ul[2][s][t] + ul[3][s][t];
    if (t < NS)
        pda[base + t] = dl[0][t] + dl[1][t] + dl[2][t] + dl[3][t];
}

// ================= per-iter: finalize -> Aavg ================================
__global__ void __launch_bounds__(256)
k_fin(const float* __restrict__ pu, const float* __restrict__ pda,
      float* __restrict__ Aavg) {
    int bb = blockIdx.x, s = blockIdx.y, t = threadIdx.x;
    __shared__ float dsh;
    if (t < 64) {
        float a = pda[((size_t)bb * NCHUNK + (t & 31)) * NS + s];
        a += DPPF(a, 0xB1);
        a += DPPF(a, 0x4E);
        a += DPPF(a, 0x124);
        a += DPPF(a, 0x128);
        a = addx16(a);
        if (t == 0) dsh = a;
    }
    const float* src = pu + ((size_t)bb * NCHUNK * NS + s) * DIM + t;
    float acc = 0.f;
#pragma unroll 8
    for (int c = 0; c < NCHUNK; c++) acc += src[(size_t)c * NS * DIM];
    __syncthreads();
    Aavg[((size_t)bb * NS + s) * DIM + t] = acc * __fdividef(1.f, dsh);
}

// ================= per-iter: GRU (4-oc uint4 + fdot2, Ksplit8) ===============
__global__ void __launch_bounds__(512)
k_gru(const float* __restrict__ Aavg, const float* __restrict__ slots,
      const unsigned* __restrict__ w2cH, const unsigned* __restrict__ whhH,
      const float* __restrict__ b2g, const float* __restrict__ bhh,
      float* __restrict__ news) {
    int bb = blockIdx.x, ot = blockIdx.y, t = threadIdx.x;
    __shared__ unsigned AlH[NS][128], SlH[NS][128];
    __shared__ float pp[7][64][24];
    for (int idx = t; idx < 1024; idx += 512) {
        int rr = idx >> 7, pi = idx & 127;
        float2 av = *(const float2*)&Aavg[(size_t)bb * 2048 + rr * 256 + 2 * pi];
        float2 sv = *(const float2*)&slots[(size_t)bb * 2048 + rr * 256 + 2 * pi];
        AlH[rr][pi] = pkh(av.x, av.y);
        SlH[rr][pi] = pkh(sv.x, sv.y);
    }
    __syncthreads();
    int q = t & 7, r = (t >> 3) & 7, kp = t >> 6;
    int oc0 = ot * 32 + q * 4;
    float ir[4] = {}, iz[4] = {}, in_[4] = {}, hr[4] = {}, hz[4] = {}, hn[4] = {};
    int p0 = kp * 16;
#pragma unroll 4
    for (int i = 0; i < 16; i++) {
        int ep = p0 + i;
        uint4 w0 = *(const uint4*)&w2cH[(size_t)ep * 768 + oc0];
        uint4 w1 = *(const uint4*)&w2cH[(size_t)ep * 768 + oc0 + 256];
        uint4 w2 = *(const uint4*)&w2cH[(size_t)ep * 768 + oc0 + 512];
        uint4 u0 = *(const uint4*)&whhH[(size_t)ep * 768 + oc0];
        uint4 u1 = *(const uint4*)&whhH[(size_t)ep * 768 + oc0 + 256];
        uint4 u2 = *(const uint4*)&whhH[(size_t)ep * 768 + oc0 + 512];
        unsigned ah = AlH[r][ep], hh = SlH[r][ep];
        const unsigned* w0u = (const unsigned*)&w0;
        const unsigned* w1u = (const unsigned*)&w1;
        const unsigned* w2u = (const unsigned*)&w2;
        const unsigned* u0u = (const unsigned*)&u0;
        const unsigned* u1u = (const unsigned*)&u1;
        const unsigned* u2u = (const unsigned*)&u2;
#pragma unroll
        for (int j = 0; j < 4; j++) {
            ir[j]  = fdot2u(w0u[j], ah, ir[j]);
            iz[j]  = fdot2u(w1u[j], ah, iz[j]);
            in_[j] = fdot2u(w2u[j], ah, in_[j]);
            hr[j]  = fdot2u(u0u[j], hh, hr[j]);
            hz[j]  = fdot2u(u1u[j], hh, hz[j]);
            hn[j]  = fdot2u(u2u[j], hh, hn[j]);
        }
    }
    int slot = (r << 3) | q;
    if (kp) {
        float* d = &pp[kp - 1][slot][0];
#pragma unroll
        for (int j = 0; j < 4; j++) {
            d[j] = ir[j]; d[4 + j] = iz[j]; d[8 + j] = in_[j];
            d[12 + j] = hr[j]; d[16 + j] = hz[j]; d[20 + j] = hn[j];
        }
    }
    __syncthreads();
    if (!kp) {
#pragma unroll
        for (int k = 0; k < 7; k++) {
            const float* s_ = &pp[k][slot][0];
#pragma unroll
            for (int j = 0; j < 4; j++) {
                ir[j] += s_[j]; iz[j] += s_[4 + j]; in_[j] += s_[8 + j];
                hr[j] += s_[12 + j]; hz[j] += s_[16 + j]; hn[j] += s_[20 + j];
            }
        }
        float4 hv = *(const float4*)&slots[((size_t)bb * NS + r) * DIM + oc0];
        float hvv[4] = {hv.x, hv.y, hv.z, hv.w};
        float out[4];
#pragma unroll
        for (int j = 0; j < 4; j++) {
            int oc = oc0 + j;
            float gir = ir[j] + b2g[oc], giz = iz[j] + b2g[oc + 256], gin = in_[j] + b2g[oc + 512];
            float ghr = hr[j] + bhh[oc], ghz = hz[j] + bhh[oc + 256], ghn = hn[j] + bhh[oc + 512];
            float rg = 1.f / (1.f + __expf(-(gir + ghr)));
            float zg = 1.f / (1.f + __expf(-(giz + ghz)));
            float ng = tanhf(fmaf(rg, ghn, gin));
            out[j] = fmaf(zg, hvv[j] - ng, ng);
        }
        *(float4*)&news[((size_t)bb * NS + r) * DIM + oc0] = float4{out[0], out[1], out[2], out[3]};
    }
}

// ================= per-iter: LN(news) + FF1 -> packed h1 =====================
__global__ void __launch_bounds__(512)
k_ff1(const float* __restrict__ news, const unsigned* __restrict__ f1H,
      const float* __restrict__ f1bp, unsigned* __restrict__ h1H) {
    int bb = blockIdx.x, ht = blockIdx.y, t = threadIdx.x;
    int wave = t >> 6, lane = t & 63;
    __shared__ unsigned ZH[NS][128];
    __shared__ float pp[3][128][4];
    {
        float4 xv = *(const float4*)&news[((size_t)bb * NS + wave) * DIM + lane * 4];
        float S, Q;
        tree2(xv.x + xv.y + xv.z + xv.w,
              xv.x * xv.x + xv.y * xv.y + xv.z * xv.z + xv.w * xv.w, lane, S, Q);
        float m = S * (1.f / DIM);
        float rstd = rsqrtf(Q * (1.f / DIM) - m * m + LN_EPS);
        ZH[wave][lane * 2]     = pkh((xv.x - m) * rstd, (xv.y - m) * rstd);
        ZH[wave][lane * 2 + 1] = pkh((xv.z - m) * rstd, (xv.w - m) * rstd);
    }
    __syncthreads();
    int cq = t & 15, r = (t >> 4) & 7, kp = t >> 7;   // 16 c-quads, 8 rows, 4 ksplit
    int c0 = ht * 64 + cq * 4;
    float acc[4] = {};
    int p0 = kp * 32;
#pragma unroll 4
    for (int i = 0; i < 32; i++) {
        int ep = p0 + i;
        uint4 wv4 = *(const uint4*)&f1H[(size_t)ep * HID + c0];
        unsigned zh = ZH[r][ep];
        const unsigned* wu = (const unsigned*)&wv4;
#pragma unroll
        for (int j = 0; j < 4; j++) acc[j] = fdot2u(wu[j], zh, acc[j]);
    }
    int slot = (r << 4) | cq;
    if (kp) {
        float* d = &pp[kp - 1][slot][0];
#pragma unroll
        for (int j = 0; j < 4; j++) d[j] = acc[j];
    }
    __syncthreads();
    if (!kp) {
#pragma unroll
        for (int k = 0; k < 3; k++) {
            const float* s_ = &pp[k][slot][0];
#pragma unroll
            for (int j = 0; j < 4; j++) acc[j] += s_[j];
        }
        float h0 = fmaxf(acc[0] + f1bp[c0 + 0], 0.f);
        float h1v = fmaxf(acc[1] + f1bp[c0 + 1], 0.f);
        float h2 = fmaxf(acc[2] + f1bp[c0 + 2], 0.f);
        float h3 = fmaxf(acc[3] + f1bp[c0 + 3], 0.f);
        uint2 st;
        st.x = pkh(h0, h1v);
        st.y = pkh(h2, h3);
        *(uint2*)&h1H[((size_t)bb * NS + r) * 256 + c0 / 2] = st;
    }
}

// ================= per-iter: FF2 + residual (4-oc uint4 + fdot2, Ksplit8) ====
__global__ void __launch_bounds__(512)
k_ff2(const unsigned* __restrict__ h1H, const unsigned* __restrict__ f2H,
      const float* __restrict__ f2b, const float* __restrict__ news,
      float* __restrict__ slots) {
    int bb = blockIdx.x, ot = blockIdx.y, t = threadIdx.x;
    __shared__ unsigned HH[NS][256];
    __shared__ float pp[7][64][4];
    for (int idx = t; idx < 512; idx += 512)
        ((uint4*)HH)[idx] = ((const uint4*)(h1H + (size_t)bb * NS * 256))[idx];
    __syncthreads();
    int q = t & 7, r = (t >> 3) & 7, kp = t >> 6;
    int oc0 = ot * 32 + q * 4;
    float acc[4] = {};
    int p0 = kp * 32;
#pragma unroll 4
    for (int i = 0; i < 32; i++) {
        int ep = p0 + i;
        uint4 wv4 = *(const uint4*)&f2H[(size_t)ep * 256 + oc0];
        unsigned hh = HH[r][ep];
        const unsigned* wu = (const unsigned*)&wv4;
#pragma unroll
        for (int j = 0; j < 4; j++) acc[j] = fdot2u(wu[j], hh, acc[j]);
    }
    int slot = (r << 3) | q;
    if (kp) {
        float* d = &pp[kp - 1][slot][0];
#pragma unroll
        for (int j = 0; j < 4; j++) d[j] = acc[j];
    }
    __syncthreads();
    if (!kp) {
#pragma unroll
        for (int k = 0; k < 7; k++) {
            const float* s_ = &pp[k][slot][0];
#pragma unroll
            for (int j = 0; j < 4; j++) acc[j] += s_[j];
        }
        float4 nv = *(const float4*)&news[((size_t)bb * NS + r) * DIM + oc0];
        float4 bv4 = *(const float4*)&f2b[oc0];
        float4 out = {nv.x + acc[0] + bv4.x, nv.y + acc[1] + bv4.y,
                      nv.z + acc[2] + bv4.z, nv.w + acc[3] + bv4.w};
        *(float4*)&slots[((size_t)bb * NS + r) * DIM + oc0] = out;
    }
}

// ================= per-iter: LN(slots) + qk + c2 (4-oc uint4, Ksplit8) =======
__global__ void __launch_bounds__(512)
k_qk2(const float* __restrict__ slots, const unsigned* __restrict__ MppH,
      const float* __restrict__ biasp, const float* __restrict__ u2p,
      float* __restrict__ qkw, float* __restrict__ c2b) {
    int bb = blockIdx.x, ot = blockIdx.y, t = threadIdx.x;
    int wave = t >> 6, lane = t & 63;
    __shared__ unsigned ZH[NS][128];
    __shared__ float pp[7][64][4];
    {
        float4 xv = *(const float4*)&slots[((size_t)bb * NS + wave) * DIM + lane * 4];
        float S, Q;
        tree2(xv.x + xv.y + xv.z + xv.w,
              xv.x * xv.x + xv.y * xv.y + xv.z * xv.z + xv.w * xv.w, lane, S, Q);
        float m = S * (1.f / DIM);
        float rstd = rsqrtf(Q * (1.f / DIM) - m * m + LN_EPS);
        ZH[wave][lane * 2]     = pkh((xv.x - m) * rstd, (xv.y - m) * rstd);
        ZH[wave][lane * 2 + 1] = pkh((xv.z - m) * rstd, (xv.w - m) * rstd);
    }
    __syncthreads();
    int q = t & 7, r = (t >> 3) & 7, kp = t >> 6;
    int oc0 = ot * 32 + q * 4;
    float acc[4] = {};
    int p0 = kp * 16;
#pragma unroll 4
    for (int i = 0; i < 16; i++) {
        int ep = p0 + i;
        uint4 wv4 = *(const uint4*)&MppH[(size_t)ep * 256 + oc0];
        unsigned zh = ZH[r][ep];
        const unsigned* wu = (const unsigned*)&wv4;
#pragma unroll
        for (int j = 0; j < 4; j++) acc[j] = fdot2u(wu[j], zh, acc[j]);
    }
    int slot = (r << 3) | q;
    if (kp) {
        float* d = &pp[kp - 1][slot][0];
#pragma unroll
        for (int j = 0; j < 4; j++) d[j] = acc[j];
    }
    __syncthreads();
    if (!kp) {
#pragma unroll
        for (int k = 0; k < 7; k++) {
            const float* s_ = &pp[k][slot][0];
#pragma unroll
            for (int j = 0; j < 4; j++) acc[j] += s_[j];
        }
        float4 bv4 = *(const float4*)&biasp[oc0];
        float4 out = {acc[0] + bv4.x, acc[1] + bv4.y, acc[2] + bv4.z, acc[3] + bv4.w};
        *(float4*)&qkw[((size_t)bb * NS + r) * DIM + oc0] = out;
    }
    if (ot == 0 && t < 64) {
        int s = t >> 3, j = t & 7;
        float a = 0.f;
        for (int p = j * 16; p < j * 16 + 16; p++) {
            float2 z = h2f2(ZH[s][p]);
            a = fmaf(z.x, u2p[2 * p], fmaf(z.y, u2p[2 * p + 1], a));
        }
        a += DPPF(a, 0xB1);
        a += DPPF(a, 0x4E);
        a += DPPF(a, 0x141);
        if (j == 0) c2b[bb * NS + s] = a + biasp[256];
    }
}

extern "C" void kernel_launch(void* const* d_in, const int* in_sizes, int n_in,
                              void* d_out, int out_size, void* d_ws, size_t ws_size,
                              hipStream_t stream) {
    const float* x     = (const float*)d_in[0];
    const float* noise = (const float*)d_in[1];
    const float* mu  = (const float*)d_in[3];
    const float* sg  = (const float*)d_in[4];
    const float* wq  = (const float*)d_in[5];
    const float* bq  = (const float*)d_in[6];
    const float* wk  = (const float*)d_in[7];
    const float* bk  = (const float*)d_in[8];
    const float* wv  = (const float*)d_in[9];
    const float* bv  = (const float*)d_in[10];
    const float* wih = (const float*)d_in[11];
    const float* whh = (const float*)d_in[12];
    const float* bih = (const float*)d_in[13];
    const float* bhh = (const float*)d_in[14];
    const float* f1w = (const float*)d_in[15];
    const float* f1b = (const float*)d_in[16];
    const float* f2w = (const float*)d_in[17];
    const float* f2b = (const float*)d_in[18];
    const float* liw = (const float*)d_in[19];
    const float* lib = (const float*)d_in[20];
    const float* lsw = (const float*)d_in[21];
    const float* lsb = (const float*)d_in[22];
    const float* lfw = (const float*)d_in[23];
    const float* lfb = (const float*)d_in[24];
    float* slots = (float*)d_out;

    __half* xh = (__half*)d_ws;                         // 64 MB
    float* p = (float*)(xh + (size_t)NB * NTOK * DIM);
    unsigned* MppH = (unsigned*)p; p += 128 * 256;
    unsigned* w2cH = (unsigned*)p; p += 128 * 768;
    unsigned* whhH = (unsigned*)p; p += 128 * 768;
    unsigned* f1H  = (unsigned*)p; p += 128 * 512;
    unsigned* f2H  = (unsigned*)p; p += 256 * 256;
    unsigned* h1H  = (unsigned*)p; p += NROWS * 256;
    float* u2p   = p; p += 256;
    float* biasp = p; p += 257;
    float* f1bp  = p; p += 512;
    float* b2g   = p; p += 768;
    float* qkw   = p; p += NROWS * 256;
    float* c2b   = p; p += NROWS;
    float* pu    = p; p += (size_t)NB * NCHUNK * NS * DIM;
    float* pda   = p; p += NB * NCHUNK * NS;
    float* Aavg  = p; p += NROWS * 256;
    float* news  = p; p += NROWS * 256;

    k_wprep<<<WP_BLKS, 256, 0, stream>>>(
        wq, wk, bk, bq, lsb, lsw, MppH, u2p, biasp,
        wv, wih, w2cH,
        f1w, f1b, lfb, f1bp,
        bih, bv, b2g,
        whh, f2w, lfw, whhH, f1H, f2H);
    k_xn<<<2048, 256, 0, stream>>>(x, liw, lib, xh);
    k_iq<<<NB, 512, 0, stream>>>(noise, mu, sg, slots, MppH, biasp, u2p, qkw, c2b);

    for (int it = 0; it < 3; it++) {
        k_attn<<<dim3(NB, NCHUNK), 256, 0, stream>>>(xh, qkw, c2b, pu, pda);
        k_fin<<<dim3(NB, NS), 256, 0, stream>>>(pu, pda, Aavg);
        k_gru<<<dim3(NB, NS), 512, 0, stream>>>(Aavg, slots, w2cH, whhH, b2g, bhh, news);
        k_ff1<<<dim3(NB, NS), 512, 0, stream>>>(news, f1H, f1bp, h1H);
        k_ff2<<<dim3(NB, NS), 512, 0, stream>>>(h1H, f2H, f2b, news, slots);
        if (it < 2)
            k_qk2<<<dim3(NB, NS), 512, 0, stream>>>(slots, MppH, biasp, u2p, qkw, c2b);
    }
}

// Round 11
// 227.529 us; speedup vs baseline: 2.1188x; 1.0106x over previous
//
#include <hip/hip_runtime.h>
#include <hip/hip_fp16.h>
#include <math.h>

#define NB 32
#define NTOK 4096
#define DIM 256
#define NS 8
#define HID 512
#define NCHUNK 32
#define LN_EPS 1e-5f
#define ATT_EPS 1e-8f
#define SCALE 0.0625f
#define NROWS (NB * NS)   // 256

// ---- cross-lane primitives (VALU-pipe: DPP / permlane) ---------------------
#define DPPF(x, ctrl) __int_as_float(__builtin_amdgcn_update_dpp(0, __float_as_int(x), (ctrl), 0xF, 0xF, true))
// 0xB1 quad_perm xor1, 0x4E quad_perm xor2, 0x141 row_half_mirror (xor7),
// 0x124 row_ror:4, 0x128 row_ror:8

__device__ __forceinline__ float addx16(float c) {
#if __has_builtin(__builtin_amdgcn_permlane16_swap)
    auto r = __builtin_amdgcn_permlane16_swap(__float_as_uint(c), __float_as_uint(c), false, false);
    return __uint_as_float(r[0]) + __uint_as_float(r[1]);
#else
    return c + __shfl_xor(c, 16);
#endif
}
__device__ __forceinline__ float addx32(float c) {
#if __has_builtin(__builtin_amdgcn_permlane32_swap)
    auto r = __builtin_amdgcn_permlane32_swap(__float_as_uint(c), __float_as_uint(c), false, false);
    return __uint_as_float(r[0]) + __uint_as_float(r[1]);
#else
    return c + __shfl_xor(c, 32);
#endif
}

// sum + sumsq over 64 lanes, both results in every lane.
__device__ __forceinline__ void tree2(float v0, float v1, int lane, float& S, float& Q) {
    bool hi = lane & 1;
    float send = hi ? v0 : v1;
    float recv = DPPF(send, 0xB1);
    float a = (hi ? v1 : v0) + recv;
    a += DPPF(a, 0x4E);
    a += DPPF(a, 0x124);
    a += DPPF(a, 0x128);
    a = addx16(a);
    a = addx32(a);
    float other = DPPF(a, 0xB1);
    S = hi ? other : a;
    Q = hi ? a : other;
}

// 8 independent sums over a 32-lane half-wave; lane ends with full half-wave
// sum of slot sig(lane) = (l0<<2)|(l1<<1)|(l0^l1^l2).
__device__ __forceinline__ float tree8h(const float v[8], int lane) {
    bool b0 = lane & 1;
    bool b1 = lane & 2;
    bool bp = ((lane ^ (lane >> 1) ^ (lane >> 2)) & 1);
    float a[4];
#pragma unroll
    for (int j = 0; j < 4; j++) {
        float send = b0 ? v[j] : v[4 + j];
        float recv = DPPF(send, 0xB1);
        a[j] = (b0 ? v[4 + j] : v[j]) + recv;
    }
    float b[2];
#pragma unroll
    for (int j = 0; j < 2; j++) {
        float send = b1 ? a[j] : a[2 + j];
        float recv = DPPF(send, 0x4E);
        b[j] = (b1 ? a[2 + j] : a[j]) + recv;
    }
    float send = bp ? b[0] : b[1];
    float recv = DPPF(send, 0x141);
    float c = (bp ? b[1] : b[0]) + recv;
    c += DPPF(c, 0x128);
    c = addx16(c);
    return c;
}

typedef _Float16 h2v __attribute__((ext_vector_type(2)));
typedef float f32x2 __attribute__((ext_vector_type(2)));
__device__ __forceinline__ float fdot2u(unsigned a, unsigned b, float c) {
#if __has_builtin(__builtin_amdgcn_fdot2)
    return __builtin_amdgcn_fdot2(__builtin_bit_cast(h2v, a), __builtin_bit_cast(h2v, b), c, false);
#else
    __half2 ha = __builtin_bit_cast(__half2, a), hb = __builtin_bit_cast(__half2, b);
    return c + __low2float(ha) * __low2float(hb) + __high2float(ha) * __high2float(hb);
#endif
}
__device__ __forceinline__ unsigned pkh(float a, float b) {
    return __builtin_bit_cast(unsigned, __floats2half2_rn(a, b));
}
__device__ __forceinline__ float2 h2f2(unsigned u) {
    __half2 h = __builtin_bit_cast(__half2, u);
    return float2{__low2float(h), __high2float(h)};
}
__device__ __forceinline__ f32x2 h2f2v(unsigned u) {
    __half2 h = __builtin_bit_cast(__half2, u);
    return f32x2{__low2float(h), __high2float(h)};
}
// packed 2x f32 FMA: acc = a*b + acc  (CDNA v_pk_fma_f32, full-rate)
__device__ __forceinline__ void pkfma(f32x2& acc, f32x2 a, f32x2 b) {
    asm("v_pk_fma_f32 %0, %1, %2, %0" : "+v"(acc) : "v"(a), "v"(b));
}

// ================= K1: merged setup (xn + weight prep, role-switched) ========
// [0,2048)   xn: LN(x)*liw+lib -> f16, 64 rows/block (row-per-wave)
// then wprep roles offset by XN_OFF:
#define XN_OFF   2048
#define WP_BIAS  (XN_OFF + 128)
#define WP_WHH0  (XN_OFF + 129)
#define WP_F1H0  (XN_OFF + 225)
#define WP_F2H0  (XN_OFF + 289)
#define WP_W2C0  (XN_OFF + 353)
#define WP_F1B0  (XN_OFF + 401)
#define WP_B2G0  (XN_OFF + 403)
#define WP_BLKS  (XN_OFF + 406)

__global__ void __launch_bounds__(256)
k_pre(const float* __restrict__ x, const float* __restrict__ liw,
      const float* __restrict__ lib, __half* __restrict__ xh,
      const float* __restrict__ wq, const float* __restrict__ wk,
      const float* __restrict__ bk, const float* __restrict__ bq,
      const float* __restrict__ lsb, const float* __restrict__ lsw,
      unsigned* __restrict__ MppH, float* __restrict__ u2p, float* __restrict__ biasp,
      const float* __restrict__ wv, const float* __restrict__ wih,
      unsigned* __restrict__ w2cH,
      const float* __restrict__ f1w, const float* __restrict__ f1b,
      const float* __restrict__ lfb, float* __restrict__ f1bp,
      const float* __restrict__ bih, const float* __restrict__ bv,
      float* __restrict__ b2g,
      const float* __restrict__ whh, const float* __restrict__ f2w,
      const float* __restrict__ lfw,
      unsigned* __restrict__ whhH, unsigned* __restrict__ f1H,
      unsigned* __restrict__ f2H) {
    int bid = blockIdx.x, t = threadIdx.x;

    if (bid < XN_OFF) {                        // ---- xn -> f16
        int wave = t >> 6, lane = t & 63;
        float4 w4 = *(const float4*)&liw[lane * 4];
        float4 b4 = *(const float4*)&lib[lane * 4];
        size_t rbase = (size_t)bid * 64 + wave;
        float4 cur = *(const float4*)&x[rbase * 256 + lane * 4];
        for (int i = 0; i < 16; i++) {
            float4 nxt;
            if (i < 15) nxt = *(const float4*)&x[(rbase + (size_t)(i + 1) * 4) * 256 + lane * 4];
            float S, Q;
            tree2(cur.x + cur.y + cur.z + cur.w,
                  cur.x * cur.x + cur.y * cur.y + cur.z * cur.z + cur.w * cur.w, lane, S, Q);
            float m = S * (1.f / DIM);
            float rstd = rsqrtf(Q * (1.f / DIM) - m * m + LN_EPS);
            uint2 st;
            st.x = pkh((cur.x - m) * rstd * w4.x + b4.x, (cur.y - m) * rstd * w4.y + b4.y);
            st.y = pkh((cur.z - m) * rstd * w4.z + b4.z, (cur.w - m) * rstd * w4.w + b4.w);
            *(uint2*)&xh[(rbase + (size_t)i * 4) * 256 + lane * 4] = st;
            cur = nxt;
        }
        return;
    }
    if (bid < WP_BIAS) {                       // ---- MppH: e-pair (2b, 2b+1)
        int b = bid - XN_OFF, o = t;
        float a0 = 0.f, a1 = 0.f;
        for (int d = 0; d < 256; d++) {
            float2 wqp = *(const float2*)&wq[(size_t)d * 256 + 2 * b];
            float wkv = wk[(size_t)d * 256 + o];
            a0 = fmaf(wqp.x, wkv, a0);
            a1 = fmaf(wqp.y, wkv, a1);
        }
        MppH[(size_t)b * 256 + o] = pkh(a0 * lsw[2 * b], a1 * lsw[2 * b + 1]);
        return;
    }
    if (bid == WP_BIAS) {                      // ---- biasp / u2p / k2
        int o = t;
        __shared__ float t2l[256], bkl[256], red[4];
        bkl[o] = bk[o];
        float a = bq[o];
        for (int k = 0; k < 256; k++) a = fmaf(wq[(size_t)o * 256 + k], lsb[k], a);
        t2l[o] = a;
        __syncthreads();
        float ab = 0.f, au = 0.f;
        for (int d = 0; d < 256; d++) {
            ab = fmaf(t2l[d], wk[(size_t)d * 256 + o], ab);
            au = fmaf(bkl[d], wq[(size_t)d * 256 + o], au);
        }
        biasp[o] = ab;
        u2p[o] = au * lsw[o];
        float kk = t2l[o] * bkl[o];
        kk += DPPF(kk, 0xB1);
        kk += DPPF(kk, 0x4E);
        kk += DPPF(kk, 0x124);
        kk += DPPF(kk, 0x128);
        kk = addx16(kk);
        kk = addx32(kk);
        if ((t & 63) == 0) red[t >> 6] = kk;
        __syncthreads();
        if (t == 0) biasp[256] = red[0] + red[1] + red[2] + red[3];
        return;
    }
    if (bid < WP_W2C0) {                       // ---- transpose-pack roles
        const float* in; unsigned* out; const float* scl = nullptr;
        int C, OS, r, RT;
        if (bid < WP_F1H0)      { in = whh; out = whhH; C = 256; OS = 768; r = bid - WP_WHH0; RT = 24; }
        else if (bid < WP_F2H0) { in = f1w; out = f1H;  C = 256; OS = 512; r = bid - WP_F1H0; RT = 16; scl = lfw; }
        else                    { in = f2w; out = f2H;  C = 512; OS = 256; r = bid - WP_F2H0; RT = 8; }
        int otl = r % RT, ept = r / RT;
        __shared__ float tile[32][65];
#pragma unroll
        for (int i = 0; i < 8; i++) {
            int idx = t + i * 256;
            int row = idx >> 6, col = idx & 63;
            tile[row][col] = in[(size_t)(otl * 32 + row) * C + ept * 64 + col];
        }
        __syncthreads();
#pragma unroll
        for (int i = 0; i < 4; i++) {
            int idx = t + i * 256;
            int epl = idx >> 5, ol = idx & 31;
            float v0 = tile[ol][2 * epl], v1 = tile[ol][2 * epl + 1];
            if (scl) { v0 *= scl[ept * 64 + 2 * epl]; v1 *= scl[ept * 64 + 2 * epl + 1]; }
            out[(size_t)(ept * 32 + epl) * OS + otl * 32 + ol] = pkh(v0, v1);
        }
        return;
    }
    if (bid < WP_F1B0) {                       // ---- w2cH
        int r = bid - WP_W2C0;
        int et = r & 3, ot = r >> 2;
        int ep = et * 32 + (t & 31), og = (t >> 5) * 8;
        float alo[8] = {}, ahi[8] = {};
        for (int d = 0; d < 256; d++) {
            float2 wvp = *(const float2*)&wv[(size_t)d * 256 + 2 * ep];
#pragma unroll
            for (int i = 0; i < 8; i++) {
                float wv_ih = wih[(size_t)(ot * 64 + og + i) * 256 + d];
                alo[i] = fmaf(wvp.x, wv_ih, alo[i]);
                ahi[i] = fmaf(wvp.y, wv_ih, ahi[i]);
            }
        }
#pragma unroll
        for (int i = 0; i < 8; i++)
            w2cH[(size_t)ep * 768 + ot * 64 + og + i] = pkh(alo[i], ahi[i]);
        return;
    }
    if (bid < WP_B2G0) {                       // ---- f1bp
        int h = (bid - WP_F1B0) * 256 + t;
        float a = f1b[h];
        for (int e = 0; e < 256; e++) a = fmaf(f1w[(size_t)h * 256 + e], lfb[e], a);
        f1bp[h] = a;
        return;
    }
    {                                          // ---- b2g
        int o = (bid - WP_B2G0) * 256 + t;
        float a = bih[o];
        for (int d = 0; d < 256; d++) a = fmaf(wih[(size_t)o * 256 + d], bv[d], a);
        b2g[o] = a;
    }
}

// ================= K2: slots init + first qk =================================
__global__ void __launch_bounds__(512)
k_iq(const float* __restrict__ noise, const float* __restrict__ mu,
     const float* __restrict__ sg, float* __restrict__ slots,
     const unsigned* __restrict__ MppH, const float* __restrict__ biasp,
     const float* __restrict__ u2p,
     float* __restrict__ qkw, float* __restrict__ c2b) {
    int bb = blockIdx.x, t = threadIdx.x, wave = t >> 6, lane = t & 63;
    __shared__ float S2[NS][DIM], Zl[NS][DIM];
#pragma unroll
    for (int k = 0; k < 4; k++) {
        int idx = k * 512 + t, d = idx & 255;
        float v = mu[d] + sg[d] * noise[(size_t)bb * 2048 + idx];
        S2[idx >> 8][d] = v;
        slots[(size_t)bb * 2048 + idx] = v;
    }
    __syncthreads();
    {
        float4 xv = *(const float4*)&S2[wave][lane * 4];
        float S, Q;
        tree2(xv.x + xv.y + xv.z + xv.w,
              xv.x * xv.x + xv.y * xv.y + xv.z * xv.z + xv.w * xv.w, lane, S, Q);
        float m = S * (1.f / DIM);
        float rstd = rsqrtf(Q * (1.f / DIM) - m * m + LN_EPS);
        Zl[wave][lane * 4 + 0] = (xv.x - m) * rstd;
        Zl[wave][lane * 4 + 1] = (xv.y - m) * rstd;
        Zl[wave][lane * 4 + 2] = (xv.z - m) * rstd;
        Zl[wave][lane * 4 + 3] = (xv.w - m) * rstd;
    }
    __syncthreads();
    int o = t & 255, sg2 = (t >> 8) * 4;
    float acc[4] = {};
    for (int ep = 0; ep < 128; ep++) {
        float2 wf = h2f2(MppH[(size_t)ep * 256 + o]);
#pragma unroll
        for (int i = 0; i < 4; i++) {
            float2 zp = *(const float2*)&Zl[sg2 + i][2 * ep];
            acc[i] = fmaf(zp.x, wf.x, fmaf(zp.y, wf.y, acc[i]));
        }
    }
    float bo = biasp[o];
#pragma unroll
    for (int i = 0; i < 4; i++)
        qkw[(size_t)(bb * NS + sg2 + i) * DIM + o] = acc[i] + bo;
    if (t < 64) {
        int s = t >> 3, j = t & 7;
        float a = 0.f;
        for (int e = j * 32; e < j * 32 + 32; e++) a = fmaf(Zl[s][e], u2p[e], a);
        a += DPPF(a, 0xB1);
        a += DPPF(a, 0x4E);
        a += DPPF(a, 0x141);
        if (j == 0) c2b[bb * NS + s] = a + biasp[256];
    }
}

// ================= per-iter: fused attention (pk_fma accumulate) =============
__global__ void __launch_bounds__(256, 3)
k_attn(const __half* __restrict__ xh, const float* __restrict__ qkw,
       const float* __restrict__ c2b,
       unsigned* __restrict__ puH, float* __restrict__ pda) {
    const int bb = blockIdx.x, chunk = blockIdx.y;
    const int t = threadIdx.x, wave = t >> 6, lane = t & 63;
    const int l0 = lane & 1, l1 = (lane >> 1) & 1, l2 = (lane >> 2) & 1;
    const int sig = (l0 << 2) | (l1 << 1) | (l0 ^ l1 ^ l2);
    const int e0 = (lane & 31) * 8;

    unsigned qh[NS][4];
#pragma unroll
    for (int s = 0; s < NS; s++) {
        const float4 a = *(const float4*)&qkw[(size_t)(bb * NS + s) * DIM + e0];
        const float4 b = *(const float4*)&qkw[(size_t)(bb * NS + s) * DIM + e0 + 4];
        qh[s][0] = pkh(a.x, a.y); qh[s][1] = pkh(a.z, a.w);
        qh[s][2] = pkh(b.x, b.y); qh[s][3] = pkh(b.z, b.w);
    }
    const float qbs = c2b[bb * NS + sig] * SCALE;

    f32x2 ua2[NS][4] = {};
    float da[NS] = {};

    const __half* xp = xh + ((size_t)bb * NTOK + chunk * 128 + wave * 32 + (lane >> 5)) * DIM + e0;
    uint4 nxt = *(const uint4*)xp;
    for (int i = 0; i < 16; i++) {
        uint4 xv = nxt;
        if (i < 15) nxt = *(const uint4*)(xp + (size_t)(i + 1) * 2 * DIM);
        float dp[NS];
#pragma unroll
        for (int s = 0; s < NS; s++)
            dp[s] = fdot2u(qh[s][0], xv.x, fdot2u(qh[s][1], xv.y,
                    fdot2u(qh[s][2], xv.z, fdot2u(qh[s][3], xv.w, 0.f))));
        float ds = tree8h(dp, lane);
        float dv = fmaf(ds, SCALE, qbs);
        float mx = dv;
        mx = fmaxf(mx, DPPF(mx, 0xB1));
        mx = fmaxf(mx, DPPF(mx, 0x4E));
        mx = fmaxf(mx, DPPF(mx, 0x141));
        float e = __expf(dv - mx);
        float sm = e;
        sm += DPPF(sm, 0xB1);
        sm += DPPF(sm, 0x4E);
        sm += DPPF(sm, 0x141);
        float g0 = fmaf(e, __fdividef(1.f, sm), ATT_EPS);
        float g1 = DPPF(g0, 0x141);
        float g2 = DPPF(g0, 0x4E);
        float g3 = DPPF(g1, 0x4E);
        float g4 = DPPF(g0, 0xB1);
        float g5 = DPPF(g1, 0xB1);
        float g6 = DPPF(g2, 0xB1);
        float g7 = DPPF(g3, 0xB1);
        float gth[NS] = {g0, g1, g2, g3, g4, g5, g6, g7};
        f32x2 xd[4] = {h2f2v(xv.x), h2f2v(xv.y), h2f2v(xv.z), h2f2v(xv.w)};
#pragma unroll
        for (int j = 0; j < NS; j++) {
            float pj = gth[j];
            da[j] += pj;
            f32x2 pj2 = {pj, pj};
#pragma unroll
            for (int k = 0; k < 4; k++) pkfma(ua2[j][k], xd[k], pj2);
        }
    }
#pragma unroll
    for (int j = 0; j < NS; j++) {
        da[j] = addx32(da[j]);
#pragma unroll
        for (int k = 0; k < 4; k++) {
            ua2[j][k].x = addx32(ua2[j][k].x);
            ua2[j][k].y = addx32(ua2[j][k].y);
        }
    }
    __shared__ unsigned ulH[4][NS][128];
    __shared__ float dl[4][NS];
    const int M8[NS] = {0, 7, 3, 4, 5, 2, 6, 1};
    if (lane < 32) {
        int c0 = lane * 4;
#pragma unroll
        for (int j = 0; j < NS; j++) {
            int sj = sig ^ M8[j];
#pragma unroll
            for (int k = 0; k < 4; k++)
                ulH[wave][sj][c0 + k] = pkh(ua2[j][k].x, ua2[j][k].y);
        }
    }
    if (lane < 8) {
#pragma unroll
        for (int j = 0; j < NS; j++) dl[wave][sig ^ M8[j]] = da[j];
    }
    __syncthreads();
    size_t base = ((size_t)bb * NCHUNK + chunk) * NS;
    int pi = t & 127, sh = t >> 7;
#pragma unroll
    for (int q = 0; q < 4; q++) {
        int s = sh * 4 + q;
        f32x2 acc = h2f2v(ulH[0][s][pi]);
        f32x2 a1 = h2f2v(ulH[1][s][pi]);
        f32x2 a2 = h2f2v(ulH[2][s][pi]);
        f32x2 a3 = h2f2v(ulH[3][s][pi]);
        acc.x += a1.x + a2.x + a3.x;
        acc.y += a1.y + a2.y + a3.y;
        puH[(base + s) * 128 + pi] = pkh(acc.x, acc.y);
    }
    if (t < NS)
        pda[base + t] = dl[0][t] + dl[1][t] + dl[2][t] + dl[3][t];
}

// ================= per-iter: fin + GRU fused (grid 32x8, 512 thr) ============
__global__ void __launch_bounds__(512)
k_fingru(const unsigned* __restrict__ puH, const float* __restrict__ pda,
         const float* __restrict__ slots,
         const unsigned* __restrict__ w2cH, const unsigned* __restrict__ whhH,
         const float* __restrict__ b2g, const float* __restrict__ bhh,
         float* __restrict__ news) {
    int bb = blockIdx.x, ot = blockIdx.y, t = threadIdx.x;
    __shared__ unsigned AlH[NS][128], SlH[NS][128];
    __shared__ float pp[7][64][24];
    __shared__ float den[NS];
    // den[s] = sum_c pda
    if (t < 64) {
        int s = t & 7, cg = t >> 3;
        float a = 0.f;
#pragma unroll
        for (int c = 0; c < 4; c++)
            a += pda[((size_t)bb * NCHUNK + cg * 4 + c) * NS + s];
        a += DPPF(a, 0x128);
        a = addx16(a);
        a = addx32(a);
        if (t < 8) den[s] = a;
    }
    // SlH pack
#pragma unroll
    for (int k = 0; k < 2; k++) {
        int idx = t + k * 512;
        int rr = idx >> 7, pi2 = idx & 127;
        float2 sv = *(const float2*)&slots[(size_t)bb * 2048 + rr * 256 + 2 * pi2];
        SlH[rr][pi2] = pkh(sv.x, sv.y);
    }
    // raw pu chunk-sums (2 packed indices per thread)
    f32x2 raw[2];
#pragma unroll
    for (int k = 0; k < 2; k++) {
        int idx = t + k * 512;
        int s = idx >> 7, pi2 = idx & 127;
        f32x2 a = {0.f, 0.f};
        const unsigned* src = puH + ((size_t)bb * NCHUNK * NS + s) * 128 + pi2;
#pragma unroll 8
        for (int c = 0; c < NCHUNK; c++) {
            f32x2 v = h2f2v(src[(size_t)c * NS * 128]);
            a.x += v.x; a.y += v.y;
        }
        raw[k] = a;
    }
    __syncthreads();
#pragma unroll
    for (int k = 0; k < 2; k++) {
        int idx = t + k * 512;
        int s = idx >> 7, pi2 = idx & 127;
        float inv = __fdividef(1.f, den[s]);
        AlH[s][pi2] = pkh(raw[k].x * inv, raw[k].y * inv);
    }
    __syncthreads();
    // GRU (4-oc uint4 + fdot2, Ksplit8)
    int q = t & 7, r = (t >> 3) & 7, kp = t >> 6;
    int oc0 = ot * 32 + q * 4;
    float ir[4] = {}, iz[4] = {}, in_[4] = {}, hr[4] = {}, hz[4] = {}, hn[4] = {};
    int p0 = kp * 16;
#pragma unroll 4
    for (int i = 0; i < 16; i++) {
        int ep = p0 + i;
        uint4 w0 = *(const uint4*)&w2cH[(size_t)ep * 768 + oc0];
        uint4 w1 = *(const uint4*)&w2cH[(size_t)ep * 768 + oc0 + 256];
        uint4 w2 = *(const uint4*)&w2cH[(size_t)ep * 768 + oc0 + 512];
        uint4 u0 = *(const uint4*)&whhH[(size_t)ep * 768 + oc0];
        uint4 u1 = *(const uint4*)&whhH[(size_t)ep * 768 + oc0 + 256];
        uint4 u2 = *(const uint4*)&whhH[(size_t)ep * 768 + oc0 + 512];
        unsigned ah = AlH[r][ep], hh = SlH[r][ep];
        const unsigned* w0u = (const unsigned*)&w0;
        const unsigned* w1u = (const unsigned*)&w1;
        const unsigned* w2u = (const unsigned*)&w2;
        const unsigned* u0u = (const unsigned*)&u0;
        const unsigned* u1u = (const unsigned*)&u1;
        const unsigned* u2u = (const unsigned*)&u2;
#pragma unroll
        for (int j = 0; j < 4; j++) {
            ir[j]  = fdot2u(w0u[j], ah, ir[j]);
            iz[j]  = fdot2u(w1u[j], ah, iz[j]);
            in_[j] = fdot2u(w2u[j], ah, in_[j]);
            hr[j]  = fdot2u(u0u[j], hh, hr[j]);
            hz[j]  = fdot2u(u1u[j], hh, hz[j]);
            hn[j]  = fdot2u(u2u[j], hh, hn[j]);
        }
    }
    int slot = (r << 3) | q;
    if (kp) {
        float* d = &pp[kp - 1][slot][0];
#pragma unroll
        for (int j = 0; j < 4; j++) {
            d[j] = ir[j]; d[4 + j] = iz[j]; d[8 + j] = in_[j];
            d[12 + j] = hr[j]; d[16 + j] = hz[j]; d[20 + j] = hn[j];
        }
    }
    __syncthreads();
    if (!kp) {
#pragma unroll
        for (int k = 0; k < 7; k++) {
            const float* s_ = &pp[k][slot][0];
#pragma unroll
            for (int j = 0; j < 4; j++) {
                ir[j] += s_[j]; iz[j] += s_[4 + j]; in_[j] += s_[8 + j];
                hr[j] += s_[12 + j]; hz[j] += s_[16 + j]; hn[j] += s_[20 + j];
            }
        }
        float4 hv = *(const float4*)&slots[((size_t)bb * NS + r) * DIM + oc0];
        float hvv[4] = {hv.x, hv.y, hv.z, hv.w};
        float out[4];
#pragma unroll
        for (int j = 0; j < 4; j++) {
            int oc = oc0 + j;
            float gir = ir[j] + b2g[oc], giz = iz[j] + b2g[oc + 256], gin = in_[j] + b2g[oc + 512];
            float ghr = hr[j] + bhh[oc], ghz = hz[j] + bhh[oc + 256], ghn = hn[j] + bhh[oc + 512];
            float rg = 1.f / (1.f + __expf(-(gir + ghr)));
            float zg = 1.f / (1.f + __expf(-(giz + ghz)));
            float ng = tanhf(fmaf(rg, ghn, gin));
            out[j] = fmaf(zg, hvv[j] - ng, ng);
        }
        *(float4*)&news[((size_t)bb * NS + r) * DIM + oc0] = float4{out[0], out[1], out[2], out[3]};
    }
}

// ================= per-iter: LN(news) + FF1 -> packed h1 =====================
__global__ void __launch_bounds__(512)
k_ff1(const float* __restrict__ news, const unsigned* __restrict__ f1H,
      const float* __restrict__ f1bp, unsigned* __restrict__ h1H) {
    int bb = blockIdx.x, ht = blockIdx.y, t = threadIdx.x;
    int wave = t >> 6, lane = t & 63;
    __shared__ unsigned ZH[NS][128];
    __shared__ float pp[3][128][4];
    {
        float4 xv = *(const float4*)&news[((size_t)bb * NS + wave) * DIM + lane * 4];
        float S, Q;
        tree2(xv.x + xv.y + xv.z + xv.w,
              xv.x * xv.x + xv.y * xv.y + xv.z * xv.z + xv.w * xv.w, lane, S, Q);
        float m = S * (1.f / DIM);
        float rstd = rsqrtf(Q * (1.f / DIM) - m * m + LN_EPS);
        ZH[wave][lane * 2]     = pkh((xv.x - m) * rstd, (xv.y - m) * rstd);
        ZH[wave][lane * 2 + 1] = pkh((xv.z - m) * rstd, (xv.w - m) * rstd);
    }
    __syncthreads();
    int cq = t & 15, r = (t >> 4) & 7, kp = t >> 7;
    int c0 = ht * 64 + cq * 4;
    float acc[4] = {};
    int p0 = kp * 32;
#pragma unroll 4
    for (int i = 0; i < 32; i++) {
        int ep = p0 + i;
        uint4 wv4 = *(const uint4*)&f1H[(size_t)ep * HID + c0];
        unsigned zh = ZH[r][ep];
        const unsigned* wu = (const unsigned*)&wv4;
#pragma unroll
        for (int j = 0; j < 4; j++) acc[j] = fdot2u(wu[j], zh, acc[j]);
    }
    int slot = (r << 4) | cq;
    if (kp) {
        float* d = &pp[kp - 1][slot][0];
#pragma unroll
        for (int j = 0; j < 4; j++) d[j] = acc[j];
    }
    __syncthreads();
    if (!kp) {
#pragma unroll
        for (int k = 0; k < 3; k++) {
            const float* s_ = &pp[k][slot][0];
#pragma unroll
            for (int j = 0; j < 4; j++) acc[j] += s_[j];
        }
        float h0 = fmaxf(acc[0] + f1bp[c0 + 0], 0.f);
        float h1v = fmaxf(acc[1] + f1bp[c0 + 1], 0.f);
        float h2 = fmaxf(acc[2] + f1bp[c0 + 2], 0.f);
        float h3 = fmaxf(acc[3] + f1bp[c0 + 3], 0.f);
        uint2 st;
        st.x = pkh(h0, h1v);
        st.y = pkh(h2, h3);
        *(uint2*)&h1H[((size_t)bb * NS + r) * 256 + c0 / 2] = st;
    }
}

// ================= per-iter: FF2 + residual (4-oc uint4 + fdot2, Ksplit8) ====
__global__ void __launch_bounds__(512)
k_ff2(const unsigned* __restrict__ h1H, const unsigned* __restrict__ f2H,
      const float* __restrict__ f2b, const float* __restrict__ news,
      float* __restrict__ slots) {
    int bb = blockIdx.x, ot = blockIdx.y, t = threadIdx.x;
    __shared__ unsigned HH[NS][256];
    __shared__ float pp[7][64][4];
    for (int idx = t; idx < 512; idx += 512)
        ((uint4*)HH)[idx] = ((const uint4*)(h1H + (size_t)bb * NS * 256))[idx];
    __syncthreads();
    int q = t & 7, r = (t >> 3) & 7, kp = t >> 6;
    int oc0 = ot * 32 + q * 4;
    float acc[4] = {};
    int p0 = kp * 32;
#pragma unroll 4
    for (int i = 0; i < 32; i++) {
        int ep = p0 + i;
        uint4 wv4 = *(const uint4*)&f2H[(size_t)ep * 256 + oc0];
        unsigned hh = HH[r][ep];
        const unsigned* wu = (const unsigned*)&wv4;
#pragma unroll
        for (int j = 0; j < 4; j++) acc[j] = fdot2u(wu[j], hh, acc[j]);
    }
    int slot = (r << 3) | q;
    if (kp) {
        float* d = &pp[kp - 1][slot][0];
#pragma unroll
        for (int j = 0; j < 4; j++) d[j] = acc[j];
    }
    __syncthreads();
    if (!kp) {
#pragma unroll
        for (int k = 0; k < 7; k++) {
            const float* s_ = &pp[k][slot][0];
#pragma unroll
            for (int j = 0; j < 4; j++) acc[j] += s_[j];
        }
        float4 nv = *(const float4*)&news[((size_t)bb * NS + r) * DIM + oc0];
        float4 bv4 = *(const float4*)&f2b[oc0];
        float4 out = {nv.x + acc[0] + bv4.x, nv.y + acc[1] + bv4.y,
                      nv.z + acc[2] + bv4.z, nv.w + acc[3] + bv4.w};
        *(float4*)&slots[((size_t)bb * NS + r) * DIM + oc0] = out;
    }
}

// ================= per-iter: LN(slots) + qk + c2 (4-oc uint4, Ksplit8) =======
__global__ void __launch_bounds__(512)
k_qk2(const float* __restrict__ slots, const unsigned* __restrict__ MppH,
      const float* __restrict__ biasp, const float* __restrict__ u2p,
      float* __restrict__ qkw, float* __restrict__ c2b) {
    int bb = blockIdx.x, ot = blockIdx.y, t = threadIdx.x;
    int wave = t >> 6, lane = t & 63;
    __shared__ unsigned ZH[NS][128];
    __shared__ float pp[7][64][4];
    {
        float4 xv = *(const float4*)&slots[((size_t)bb * NS + wave) * DIM + lane * 4];
        float S, Q;
        tree2(xv.x + xv.y + xv.z + xv.w,
              xv.x * xv.x + xv.y * xv.y + xv.z * xv.z + xv.w * xv.w, lane, S, Q);
        float m = S * (1.f / DIM);
        float rstd = rsqrtf(Q * (1.f / DIM) - m * m + LN_EPS);
        ZH[wave][lane * 2]     = pkh((xv.x - m) * rstd, (xv.y - m) * rstd);
        ZH[wave][lane * 2 + 1] = pkh((xv.z - m) * rstd, (xv.w - m) * rstd);
    }
    __syncthreads();
    int q = t & 7, r = (t >> 3) & 7, kp = t >> 6;
    int oc0 = ot * 32 + q * 4;
    float acc[4] = {};
    int p0 = kp * 16;
#pragma unroll 4
    for (int i = 0; i < 16; i++) {
        int ep = p0 + i;
        uint4 wv4 = *(const uint4*)&MppH[(size_t)ep * 256 + oc0];
        unsigned zh = ZH[r][ep];
        const unsigned* wu = (const unsigned*)&wv4;
#pragma unroll
        for (int j = 0; j < 4; j++) acc[j] = fdot2u(wu[j], zh, acc[j]);
    }
    int slot = (r << 3) | q;
    if (kp) {
        float* d = &pp[kp - 1][slot][0];
#pragma unroll
        for (int j = 0; j < 4; j++) d[j] = acc[j];
    }
    __syncthreads();
    if (!kp) {
#pragma unroll
        for (int k = 0; k < 7; k++) {
            const float* s_ = &pp[k][slot][0];
#pragma unroll
            for (int j = 0; j < 4; j++) acc[j] += s_[j];
        }
        float4 bv4 = *(const float4*)&biasp[oc0];
        float4 out = {acc[0] + bv4.x, acc[1] + bv4.y, acc[2] + bv4.z, acc[3] + bv4.w};
        *(float4*)&qkw[((size_t)bb * NS + r) * DIM + oc0] = out;
    }
    if (ot == 0 && t < 64) {
        int s = t >> 3, j = t & 7;
        float a = 0.f;
        for (int p = j * 16; p < j * 16 + 16; p++) {
            float2 z = h2f2(ZH[s][p]);
            a = fmaf(z.x, u2p[2 * p], fmaf(z.y, u2p[2 * p + 1], a));
        }
        a += DPPF(a, 0xB1);
        a += DPPF(a, 0x4E);
        a += DPPF(a, 0x141);
        if (j == 0) c2b[bb * NS + s] = a + biasp[256];
    }
}

extern "C" void kernel_launch(void* const* d_in, const int* in_sizes, int n_in,
                              void* d_out, int out_size, void* d_ws, size_t ws_size,
                              hipStream_t stream) {
    const float* x     = (const float*)d_in[0];
    const float* noise = (const float*)d_in[1];
    const float* mu  = (const float*)d_in[3];
    const float* sg  = (const float*)d_in[4];
    const float* wq  = (const float*)d_in[5];
    const float* bq  = (const float*)d_in[6];
    const float* wk  = (const float*)d_in[7];
    const float* bk  = (const float*)d_in[8];
    const float* wv  = (const float*)d_in[9];
    const float* bv  = (const float*)d_in[10];
    const float* wih = (const float*)d_in[11];
    const float* whh = (const float*)d_in[12];
    const float* bih = (const float*)d_in[13];
    const float* bhh = (const float*)d_in[14];
    const float* f1w = (const float*)d_in[15];
    const float* f1b = (const float*)d_in[16];
    const float* f2w = (const float*)d_in[17];
    const float* f2b = (const float*)d_in[18];
    const float* liw = (const float*)d_in[19];
    const float* lib = (const float*)d_in[20];
    const float* lsw = (const float*)d_in[21];
    const float* lsb = (const float*)d_in[22];
    const float* lfw = (const float*)d_in[23];
    const float* lfb = (const float*)d_in[24];
    float* slots = (float*)d_out;

    __half* xh = (__half*)d_ws;                         // 64 MB
    float* p = (float*)(xh + (size_t)NB * NTOK * DIM);
    unsigned* MppH = (unsigned*)p; p += 128 * 256;
    unsigned* w2cH = (unsigned*)p; p += 128 * 768;
    unsigned* whhH = (unsigned*)p; p += 128 * 768;
    unsigned* f1H  = (unsigned*)p; p += 128 * 512;
    unsigned* f2H  = (unsigned*)p; p += 256 * 256;
    unsigned* h1H  = (unsigned*)p; p += NROWS * 256;
    unsigned* puH  = (unsigned*)p; p += (size_t)NB * NCHUNK * NS * 128;
    float* u2p   = p; p += 256;
    float* biasp = p; p += 257;
    float* f1bp  = p; p += 512;
    float* b2g   = p; p += 768;
    float* qkw   = p; p += NROWS * 256;
    float* c2b   = p; p += NROWS;
    float* pda   = p; p += NB * NCHUNK * NS;
    float* news  = p; p += NROWS * 256;

    k_pre<<<WP_BLKS, 256, 0, stream>>>(
        x, liw, lib, xh,
        wq, wk, bk, bq, lsb, lsw, MppH, u2p, biasp,
        wv, wih, w2cH,
        f1w, f1b, lfb, f1bp,
        bih, bv, b2g,
        whh, f2w, lfw, whhH, f1H, f2H);
    k_iq<<<NB, 512, 0, stream>>>(noise, mu, sg, slots, MppH, biasp, u2p, qkw, c2b);

    for (int it = 0; it < 3; it++) {
        k_attn<<<dim3(NB, NCHUNK), 256, 0, stream>>>(xh, qkw, c2b, puH, pda);
        k_fingru<<<dim3(NB, NS), 512, 0, stream>>>(puH, pda, slots, w2cH, whhH,
                                                   b2g, bhh, news);
        k_ff1<<<dim3(NB, NS), 512, 0, stream>>>(news, f1H, f1bp, h1H);
        k_ff2<<<dim3(NB, NS), 512, 0, stream>>>(h1H, f2H, f2b, news, slots);
        if (it < 2)
            k_qk2<<<dim3(NB, NS), 512, 0, stream>>>(slots, MppH, biasp, u2p, qkw, c2b);
    }
}